// Round 11
// baseline (110.995 us; speedup 1.0000x reference)
//
#include <hip/hip_runtime.h>
#include <math.h>

#define BB 16
#define CIN 64
#define HH 64
#define WW 64
#define COUT 128
#define HW 4096          // HH*WW
#define CK 576           // CIN*9
#define CKP 584          // LDS stride (shorts) for val

typedef __attribute__((ext_vector_type(8))) short short8;
typedef __attribute__((ext_vector_type(4))) short short4v;
typedef __attribute__((ext_vector_type(4))) float f32x4;

// ---- workspace layout (float indices) ----
#define OFF_OFF   0                         // B*18*HW  = 1179648 floats
#define MASK_OFF  1179648                   // B*9*HW   = 589824 floats
#define WT_OFF    1769472                   // wt2: 18*128*32 shorts = 36864 floats
#define WPM_OFF   1806336                   // wpm2: 18*32*32 shorts = 9216 floats
#define XH_OFF    1815552                   // B*HW*CIN shorts = 8388608 floats
#define SAB_OFF   10204160                  // 256 floats
#define STAT_OFF  10204416                  // 64 slots * 256 floats = 16384

__device__ __forceinline__ short f2bf(float f) {
    union { float f; unsigned u; } cv; cv.f = f;
    unsigned u = cv.u;
    unsigned r = (u + 0x7fffu + ((u >> 16) & 1u)) >> 16;
    return (short)r;
}
__device__ __forceinline__ float bf2f(short s) {
    union { unsigned u; float f; } cv;
    cv.u = ((unsigned)(unsigned short)s) << 16;
    return cv.f;
}
__device__ __forceinline__ unsigned cvt_pk_bf16(float lo, float hi) {
    unsigned r;
    asm("v_cvt_pk_bf16_f32 %0, %1, %2" : "=v"(r) : "v"(lo), "v"(hi));
    return r;
}

// ---------------------------------------------------------------------------
// Kernel A: transpose x NCHW -> NHWC bf16 (xh[b][y][x][c])
__global__ __launch_bounds__(256) void k_nhwc(const float* __restrict__ x,
                                              short* __restrict__ xh) {
    __shared__ float t[64][65];
    const int blk  = blockIdx.x;
    const int b    = blk >> 6;
    const int pos0 = (blk & 63) << 6;
    const int a    = threadIdx.x & 63;
    const int q    = threadIdx.x >> 6;
#pragma unroll
    for (int i = 0; i < 16; ++i) {
        int c = i * 4 + q;
        t[c][a] = x[((size_t)(b * CIN + c)) * HW + pos0 + a];
    }
    __syncthreads();
#pragma unroll
    for (int i = 0; i < 16; ++i) {
        int p = i * 4 + q;
        xh[((size_t)b * HW + pos0 + p) * CIN + a] = f2bf(t[a][p]);
    }
}

// ---------------------------------------------------------------------------
// Kernel B: pack weights to bf16, K-MAJOR panels.
__global__ __launch_bounds__(256) void k_pack(const float* __restrict__ wd,
                                              const float* __restrict__ wp,
                                              const float* __restrict__ wm,
                                              short* __restrict__ wt2,
                                              short* __restrict__ wpm2) {
    int i = blockIdx.x * 256 + threadIdx.x;
    if (i < 18 * 128 * 32) {
        int kc  = i >> 12;
        int rem = i & 4095;
        int co  = rem >> 5;
        int kl  = rem & 31;
        int kk  = kc * 32 + kl;
        int k   = kk >> 6;
        int c   = kk & 63;
        wt2[i] = f2bf(wd[co * CK + c * 9 + k]);
        return;
    }
    i -= 18 * 128 * 32;
    if (i < 18 * 32 * 32) {
        int kc  = i >> 10;
        int rem = i & 1023;
        int t   = rem >> 5;
        int kl  = rem & 31;
        int kk  = kc * 32 + kl;
        int k   = kk >> 6;
        int c   = kk & 63;
        float v = 0.f;
        if (t < 18)      v = wp[t * CK + c * 9 + k];
        else if (t < 27) v = wm[(t - 18) * CK + c * 9 + k];
        wpm2[i] = f2bf(v);
    }
}

// ---------------------------------------------------------------------------
// conv_pm A-fragment loader
__device__ __forceinline__ short8 conv_a(const short* __restrict__ xb,
                                         int ho, int wo, int lk, int kc) {
    const int k  = kc >> 1;
    const int c0 = (kc & 1) * 32 + lk * 8;
    const int yy = ho - 1 + k / 3;
    const int xx = wo - 1 + k % 3;
    const bool valid = ((unsigned)yy < 64u) & ((unsigned)xx < 64u);
    const int yyc = min(max(yy, 0), 63);
    const int xxc = min(max(xx, 0), 63);
    short8 a = *(const short8*)&xb[(((yyc << 6) + xxc) << 6) + c0];
    if (!valid) a = (short8)0;
    return a;
}

// ---------------------------------------------------------------------------
// Kernel 1: offset/mask conv (unchanged from round 10)
__global__ __launch_bounds__(256) void k_conv_pm(const short* __restrict__ xh,
                                                 const short* __restrict__ wpm2,
                                                 const float* __restrict__ bp,
                                                 const float* __restrict__ bm,
                                                 float* __restrict__ off,
                                                 float* __restrict__ mask) {
    const int bid  = blockIdx.x;
    const int swz  = (bid & 7) * 256 + (bid >> 3);
    const int pos0 = swz * 32;
    const int b   = pos0 >> 12;
    const int ho  = (pos0 >> 6) & 63;
    const int wo0 = pos0 & 63;

    const int tid  = threadIdx.x;
    const int wv   = tid >> 6;
    const int lane = tid & 63;
    const int l15  = lane & 15;
    const int lk   = lane >> 4;
    const int mw   = wv & 1;
    const int nw   = wv >> 1;

    const int p    = mw * 16 + l15;
    const int wo   = wo0 + p;
    const int t    = nw * 16 + l15;

    const short* xb  = xh + (size_t)b * HW * CIN;
    const short* wr  = wpm2 + t * 32 + lk * 8;

    short8 ar[6], brr[6];
#pragma unroll
    for (int i = 0; i < 6; ++i) {
        ar[i]  = conv_a(xb, ho, wo, lk, i);
        brr[i] = *(const short8*)&wr[i * 1024];
    }
    f32x4 acc = (f32x4)(0.f);
#pragma unroll
    for (int kc = 0; kc < 18; ++kc) {
        acc = __builtin_amdgcn_mfma_f32_16x16x32_bf16(ar[kc % 6], brr[kc % 6], acc, 0, 0, 0);
        if (kc + 6 < 18) {
            ar[kc % 6]  = conv_a(xb, ho, wo, lk, kc + 6);
            brr[kc % 6] = *(const short8*)&wr[(kc + 6) * 1024];
        }
    }

    const int pst = wo0 + mw * 16 + lk * 4;
    if (t < 18) {
        float bias = bp[t];
        float4 o;
        o.x = acc[0] + bias; o.y = acc[1] + bias;
        o.z = acc[2] + bias; o.w = acc[3] + bias;
        *(float4*)&off[(((size_t)b * 18 + t) * HH + ho) * WW + pst] = o;
    } else if (t < 27) {
        float bias = bm[t - 18];
        float4 o;
        o.x = 1.f / (1.f + expf(-(acc[0] + bias)));
        o.y = 1.f / (1.f + expf(-(acc[1] + bias)));
        o.z = 1.f / (1.f + expf(-(acc[2] + bias)));
        o.w = 1.f / (1.f + expf(-(acc[3] + bias)));
        *(float4*)&mask[(((size_t)b * 9 + (t - 18)) * HH + ho) * WW + pst] = o;
    }
}

// ---------------------------------------------------------------------------
// Kernel 2: deformable conv. MPB=16, 256 threads, 20.4KB LDS -> 8 blocks/CU
// (100% occupancy target). 8-lane gather groups (short8, half the VMEM insts).
#define MPB 16
__global__ __launch_bounds__(256) void k_deform(const short* __restrict__ xh,
                                                const float* __restrict__ off,
                                                const float* __restrict__ mask,
                                                const short* __restrict__ wt2,
                                                const float* __restrict__ bd,
                                                float* __restrict__ y,
                                                float* __restrict__ gstat) {
    __shared__ short     val[MPB * CKP];    // 18688 B
    __shared__ unsigned  s_yx[MPB * 9];     // 576 B
    __shared__ _Float16  s_wh[MPB * 9 * 4]; // 1152 B -> 20416 B total

    const int bid  = blockIdx.x;                       // 4096
    const int swz  = (bid & 7) * 512 + (bid >> 3);     // XCD-chunked (4096%8==0)
    const int pos0 = swz * MPB;
    const int b   = pos0 >> 12;
    const int ho  = (pos0 >> 6) & 63;
    const int wo0 = pos0 & 63;                         // 0,16,32,48
    const int tid = threadIdx.x;
    const int wv   = tid >> 6;
    const int lane = tid & 63;

    // ---- phase 1: sampling params (16 pos x 9 taps = 144) ----
    if (tid < MPB * 9) {
        int k = tid >> 4;            // 0..8
        int p = tid & 15;
        int wo = wo0 + p;
        float dy = off[(((size_t)b * 18 + 2 * k    ) * HH + ho) * WW + wo];
        float dx = off[(((size_t)b * 18 + 2 * k + 1) * HH + ho) * WW + wo];
        float m  = mask[(((size_t)b * 9 + k) * HH + ho) * WW + wo];
        float py = (float)(ho - 1 + k / 3) + dy;
        float px = (float)(wo - 1 + k % 3) + dx;
        float fy = floorf(py), fx = floorf(px);
        float ly = py - fy, lx = px - fx;
        int y0 = (int)fy, x0 = (int)fx;
        int y1 = y0 + 1, x1 = x0 + 1;
        float vy0 = ((unsigned)y0 < 64u) ? 1.f : 0.f;
        float vy1 = ((unsigned)y1 < 64u) ? 1.f : 0.f;
        float vx0 = ((unsigned)x0 < 64u) ? 1.f : 0.f;
        float vx1 = ((unsigned)x1 < 64u) ? 1.f : 0.f;
        int y0c = min(max(y0, 0), 63), y1c = min(max(y1, 0), 63);
        int x0c = min(max(x0, 0), 63), x1c = min(max(x1, 0), 63);
        int tt = p * 9 + k;
        s_yx[tt] = (unsigned)y0c | ((unsigned)y1c << 8) | ((unsigned)x0c << 16) | ((unsigned)x1c << 24);
        s_wh[tt * 4 + 0] = (_Float16)((1.f - ly) * (1.f - lx) * m * vy0 * vx0);
        s_wh[tt * 4 + 1] = (_Float16)((1.f - ly) * lx * m * vy0 * vx1);
        s_wh[tt * 4 + 2] = (_Float16)(ly * (1.f - lx) * m * vy1 * vx0);
        s_wh[tt * 4 + 3] = (_Float16)(ly * lx * m * vy1 * vx1);
    }
    __syncthreads();

    // ---- phase 2: gather; 8-lane groups, short8 (16B) corner loads ----
    {
        const int g  = tid >> 3;            // 0..31 groups
        const int li = tid & 7;
        const int c0 = li * 8;              // 8 channels per lane
        const short* xb = xh + (size_t)b * HW * CIN;
#pragma unroll
        for (int it = 0; it < 5; ++it) {
            int pr = it * 32 + g;           // 0..159, guard at 144
            if (pr < MPB * 9) {
                unsigned yx = s_yx[pr];
                int y0 = yx & 255, y1 = (yx >> 8) & 255;
                int x0 = (yx >> 16) & 255, x1 = yx >> 24;
                float w0 = (float)s_wh[pr * 4 + 0], w1 = (float)s_wh[pr * 4 + 1];
                float w2 = (float)s_wh[pr * 4 + 2], w3 = (float)s_wh[pr * 4 + 3];
                short8 v00 = *(const short8*)&xb[(((y0 << 6) + x0) << 6) + c0];
                short8 v01 = *(const short8*)&xb[(((y0 << 6) + x1) << 6) + c0];
                short8 v10 = *(const short8*)&xb[(((y1 << 6) + x0) << 6) + c0];
                short8 v11 = *(const short8*)&xb[(((y1 << 6) + x1) << 6) + c0];
                int p = pr / 9, k = pr - p * 9;
                union { unsigned u[4]; short8 s; } pk;
#pragma unroll
                for (int h = 0; h < 4; ++h) {
                    float fa = w0 * bf2f(v00[2*h])   + w1 * bf2f(v01[2*h])
                             + w2 * bf2f(v10[2*h])   + w3 * bf2f(v11[2*h]);
                    float fb = w0 * bf2f(v00[2*h+1]) + w1 * bf2f(v01[2*h+1])
                             + w2 * bf2f(v10[2*h+1]) + w3 * bf2f(v11[2*h+1]);
                    pk.u[h] = cvt_pk_bf16(fa, fb);
                }
                *(short8*)&val[p * CKP + (k << 6) + c0] = pk.s;   // ds_write_b128
            }
        }
    }
    __syncthreads();

    // ---- phase 3: 4 waves; wave owns co = wv*32 .. wv*32+31 (2 N-tiles) ----
    const int l15  = lane & 15;
    const int lk   = lane >> 4;

    f32x4 acc0 = (f32x4)(0.f);
    f32x4 acc1 = (f32x4)(0.f);
    const short* wq0 = wt2 + (size_t)(wv * 32 + l15) * 32 + lk * 8;
    const short* wq1 = wq0 + 16 * 32;
    const int arow = l15 * CKP + lk * 8;
#pragma unroll
    for (int kc = 0; kc < 18; ++kc) {
        short8 a  = *(const short8*)&val[arow + kc * 32];
        short8 b0 = *(const short8*)&wq0[kc * 4096];
        short8 b1 = *(const short8*)&wq1[kc * 4096];
        acc0 = __builtin_amdgcn_mfma_f32_16x16x32_bf16(a, b0, acc0, 0, 0, 0);
        acc1 = __builtin_amdgcn_mfma_f32_16x16x32_bf16(a, b1, acc1, 0, 0, 0);
    }

    // ---- epilogue: y writes (+bias) and BN partials (64-slot spread) ----
    float ls, lq;
    {
        int co0 = wv * 32 + l15;
        int co1 = co0 + 16;
        float bias0 = bd[co0], bias1 = bd[co1];
        float4 o;
        o.x = acc0[0] + bias0; o.y = acc0[1] + bias0;
        o.z = acc0[2] + bias0; o.w = acc0[3] + bias0;
        *(float4*)&y[((size_t)(b * COUT + co0)) * HW + ho * WW + wo0 + lk * 4] = o;
        o.x = acc1[0] + bias1; o.y = acc1[1] + bias1;
        o.z = acc1[2] + bias1; o.w = acc1[3] + bias1;
        *(float4*)&y[((size_t)(b * COUT + co1)) * HW + ho * WW + wo0 + lk * 4] = o;
    }
    // stats on pre-bias acc (bias folded in finalize); co0 stats in ls, co1 in lq pairs
    float s0 = acc0[0] + acc0[1] + acc0[2] + acc0[3];
    float q0 = acc0[0]*acc0[0] + acc0[1]*acc0[1] + acc0[2]*acc0[2] + acc0[3]*acc0[3];
    float s1 = acc1[0] + acc1[1] + acc1[2] + acc1[3];
    float q1 = acc1[0]*acc1[0] + acc1[1]*acc1[1] + acc1[2]*acc1[2] + acc1[3]*acc1[3];
    s0 += __shfl_xor(s0, 16); s0 += __shfl_xor(s0, 32);
    q0 += __shfl_xor(q0, 16); q0 += __shfl_xor(q0, 32);
    s1 += __shfl_xor(s1, 16); s1 += __shfl_xor(s1, 32);
    q1 += __shfl_xor(q1, 16); q1 += __shfl_xor(q1, 32);
    if (lane < 16) {
        float* slot = gstat + (bid & 63) * 256;
        int co0 = wv * 32 + lane;
        atomicAdd(&slot[co0],        s0);
        atomicAdd(&slot[128 + co0],  q0);
        atomicAdd(&slot[co0 + 16],       s1);
        atomicAdd(&slot[128 + co0 + 16], q1);
    }
}

// ---------------------------------------------------------------------------
// Kernel 3: finalize BN scale/shift (reduce 64 slots)
__global__ __launch_bounds__(128) void k_finalize(const float* __restrict__ gstat,
                                                  const float* __restrict__ bd,
                                                  const float* __restrict__ gamma,
                                                  const float* __restrict__ beta,
                                                  float* __restrict__ sAB) {
    int c = threadIdx.x;
    float s = 0.f, q = 0.f;
    for (int sl = 0; sl < 64; ++sl) {
        s += gstat[sl * 256 + c];
        q += gstat[sl * 256 + 128 + c];
    }
    const float invN = 1.f / (float)(BB * HW);
    float mean_acc = s * invN;
    float var = q * invN - mean_acc * mean_acc;
    float mean_y = mean_acc + bd[c];
    float A = gamma[c] * rsqrtf(var + 1e-5f);
    sAB[c]       = A;
    sAB[128 + c] = beta[c] - mean_y * A;
}

// ---------------------------------------------------------------------------
// Kernel 4: normalize + exact GELU (in-place on d_out)
__global__ __launch_bounds__(256) void k_norm_gelu(float* __restrict__ y,
                                                   const float* __restrict__ sAB) {
    int i4 = blockIdx.x * 256 + threadIdx.x;
    if (i4 >= (BB * COUT * HW) / 4) return;
    int c = (i4 >> 10) & 127;
    float A  = sAB[c];
    float Bc = sAB[128 + c];
    float4 v = ((const float4*)y)[i4];
    float4 r;
    float t;
    t = v.x * A + Bc; r.x = 0.5f * t * (1.f + erff(t * 0.70710678118654752f));
    t = v.y * A + Bc; r.y = 0.5f * t * (1.f + erff(t * 0.70710678118654752f));
    t = v.z * A + Bc; r.z = 0.5f * t * (1.f + erff(t * 0.70710678118654752f));
    t = v.w * A + Bc; r.w = 0.5f * t * (1.f + erff(t * 0.70710678118654752f));
    ((float4*)y)[i4] = r;
}

// ---------------------------------------------------------------------------
extern "C" void kernel_launch(void* const* d_in, const int* in_sizes, int n_in,
                              void* d_out, int out_size, void* d_ws, size_t ws_size,
                              hipStream_t stream) {
    const float* x     = (const float*)d_in[0];
    const float* w_p   = (const float*)d_in[1];
    const float* b_p   = (const float*)d_in[2];
    const float* w_m   = (const float*)d_in[3];
    const float* b_m   = (const float*)d_in[4];
    const float* w_d   = (const float*)d_in[5];
    const float* b_d   = (const float*)d_in[6];
    const float* gamma = (const float*)d_in[7];
    const float* beta  = (const float*)d_in[8];
    float* ws  = (float*)d_ws;
    float* y   = (float*)d_out;

    float* off  = ws + OFF_OFF;
    float* mask = ws + MASK_OFF;
    short* wt2  = (short*)(ws + WT_OFF);
    short* wpm2 = (short*)(ws + WPM_OFF);
    short* xh   = (short*)(ws + XH_OFF);
    float* sAB  = ws + SAB_OFF;
    float* gstat= ws + STAT_OFF;

    hipMemsetAsync(gstat, 0, 64 * 256 * sizeof(float), stream);
    k_nhwc<<<dim3(1024), dim3(256), 0, stream>>>(x, xh);
    k_pack<<<dim3((18 * 128 * 32 + 18 * 32 * 32) / 256), dim3(256), 0, stream>>>(w_d, w_p, w_m, wt2, wpm2);
    k_conv_pm<<<dim3(BB * HW / 32), dim3(256), 0, stream>>>(xh, wpm2, b_p, b_m, off, mask);
    k_deform<<<dim3(BB * HW / MPB), dim3(256), 0, stream>>>(xh, off, mask, wt2, b_d, y, gstat);
    k_finalize<<<dim3(1), dim3(128), 0, stream>>>(gstat, b_d, gamma, beta, sAB);
    k_norm_gelu<<<dim3((BB * COUT * HW / 4 + 255) / 256), dim3(256), 0, stream>>>(y, sAB);
}

// Round 12
// 106.154 us; speedup vs baseline: 1.0456x; 1.0456x over previous
//
#include <hip/hip_runtime.h>
#include <math.h>

#define BB 16
#define CIN 64
#define HH 64
#define WW 64
#define COUT 128
#define HW 4096          // HH*WW
#define CK 576           // CIN*9
#define CKP 584          // LDS stride (shorts) for val

typedef __attribute__((ext_vector_type(8))) short short8;
typedef __attribute__((ext_vector_type(4))) float f32x4;

// ---- workspace layout (float indices) ----
#define WT_OFF    0                         // wt2: 18*128*32 shorts = 36864 floats
#define WPM_OFF   36864                     // wpm2: 18*32*32 shorts = 9216 floats
#define XH_OFF    46080                     // B*HW*CIN shorts = 8388608 floats
#define SAB_OFF   8434688                   // 256 floats
#define STAT_OFF  8434944                   // 64 slots * 256 floats = 16384

__device__ __forceinline__ short f2bf(float f) {
    union { float f; unsigned u; } cv; cv.f = f;
    unsigned u = cv.u;
    unsigned r = (u + 0x7fffu + ((u >> 16) & 1u)) >> 16;
    return (short)r;
}
__device__ __forceinline__ float bf2f(short s) {
    union { unsigned u; float f; } cv;
    cv.u = ((unsigned)(unsigned short)s) << 16;
    return cv.f;
}
__device__ __forceinline__ unsigned cvt_pk_bf16(float lo, float hi) {
    unsigned r;
    asm("v_cvt_pk_bf16_f32 %0, %1, %2" : "=v"(r) : "v"(lo), "v"(hi));
    return r;
}

// ---------------------------------------------------------------------------
// Kernel A: transpose x NCHW -> NHWC bf16 (xh[b][y][x][c])
__global__ __launch_bounds__(256) void k_nhwc(const float* __restrict__ x,
                                              short* __restrict__ xh) {
    __shared__ float t[64][65];
    const int blk  = blockIdx.x;
    const int b    = blk >> 6;
    const int pos0 = (blk & 63) << 6;
    const int a    = threadIdx.x & 63;
    const int q    = threadIdx.x >> 6;
#pragma unroll
    for (int i = 0; i < 16; ++i) {
        int c = i * 4 + q;
        t[c][a] = x[((size_t)(b * CIN + c)) * HW + pos0 + a];
    }
    __syncthreads();
#pragma unroll
    for (int i = 0; i < 16; ++i) {
        int p = i * 4 + q;
        xh[((size_t)b * HW + pos0 + p) * CIN + a] = f2bf(t[a][p]);
    }
}

// ---------------------------------------------------------------------------
// Kernel B: pack weights to bf16, K-MAJOR panels.
__global__ __launch_bounds__(256) void k_pack(const float* __restrict__ wd,
                                              const float* __restrict__ wp,
                                              const float* __restrict__ wm,
                                              short* __restrict__ wt2,
                                              short* __restrict__ wpm2) {
    int i = blockIdx.x * 256 + threadIdx.x;
    if (i < 18 * 128 * 32) {
        int kc  = i >> 12;
        int rem = i & 4095;
        int co  = rem >> 5;
        int kl  = rem & 31;
        int kk  = kc * 32 + kl;
        int k   = kk >> 6;
        int c   = kk & 63;
        wt2[i] = f2bf(wd[co * CK + c * 9 + k]);
        return;
    }
    i -= 18 * 128 * 32;
    if (i < 18 * 32 * 32) {
        int kc  = i >> 10;
        int rem = i & 1023;
        int t   = rem >> 5;
        int kl  = rem & 31;
        int kk  = kc * 32 + kl;
        int k   = kk >> 6;
        int c   = kk & 63;
        float v = 0.f;
        if (t < 18)      v = wp[t * CK + c * 9 + k];
        else if (t < 27) v = wm[(t - 18) * CK + c * 9 + k];
        wpm2[i] = f2bf(v);
    }
}

// ---------------------------------------------------------------------------
// conv A-fragment loader (shifted-window NHWC patch)
__device__ __forceinline__ short8 conv_a(const short* __restrict__ xb,
                                         int ho, int wo, int lk, int kc) {
    const int k  = kc >> 1;
    const int c0 = (kc & 1) * 32 + lk * 8;
    const int yy = ho - 1 + k / 3;
    const int xx = wo - 1 + k % 3;
    const bool valid = ((unsigned)yy < 64u) & ((unsigned)xx < 64u);
    const int yyc = min(max(yy, 0), 63);
    const int xxc = min(max(xx, 0), 63);
    short8 a = *(const short8*)&xb[(((yyc << 6) + xxc) << 6) + c0];
    if (!valid) a = (short8)0;
    return a;
}

// ---------------------------------------------------------------------------
// Kernel 2: FUSED offset/mask conv + deformable conv + BN partials.
// MPB=16 positions/block, 256 threads.
//  phase 0: waves 0,1 compute the 27-ch conv tile via MFMA -> s_pm[t][p] (LDS)
//  phase 1: sampling params from s_pm
//  phase 2: bilinear gather (8-lane groups, short8)
//  phase 3: MFMA GEMM, wave owns 32 co
//  epilogue: y (+bias) stores + 64-slot spread atomics for BN stats
#define MPB 16
__global__ __launch_bounds__(256) void k_deform(const short* __restrict__ xh,
                                                const short* __restrict__ wt2,
                                                const short* __restrict__ wpm2,
                                                const float* __restrict__ bp,
                                                const float* __restrict__ bm,
                                                const float* __restrict__ bd,
                                                float* __restrict__ y,
                                                float* __restrict__ gstat) {
    __shared__ short     val[MPB * CKP];    // 18688 B
    __shared__ float     s_pm[28][MPB];     // 1792 B  conv outputs [t][p], t<27 valid
    __shared__ unsigned  s_yx[MPB * 9];     // 576 B
    __shared__ _Float16  s_wh[MPB * 9 * 4]; // 1152 B  -> 22208 B total

    const int bid  = blockIdx.x;                       // 4096
    const int swz  = (bid & 7) * 512 + (bid >> 3);     // XCD-chunked
    const int pos0 = swz * MPB;
    const int b   = pos0 >> 12;
    const int ho  = (pos0 >> 6) & 63;
    const int wo0 = pos0 & 63;                         // 0,16,32,48
    const int tid = threadIdx.x;
    const int wv   = tid >> 6;
    const int lane = tid & 63;
    const int l15  = lane & 15;
    const int lk   = lane >> 4;

    const short* xb = xh + (size_t)b * HW * CIN;

    // ---- phase 0: offset/mask conv (waves 0,1), 18 MFMAs each, N=16 ----
    if (wv < 2) {
        const int t = wv * 16 + l15;                   // out channel (t>=27: zero wt)
        const short* wr = wpm2 + t * 32 + lk * 8;
        f32x4 acc = (f32x4)(0.f);
#pragma unroll
        for (int kc = 0; kc < 18; ++kc) {
            short8 a = conv_a(xb, ho, wo0 + l15, lk, kc);
            short8 bf = *(const short8*)&wr[kc * 1024];
            acc = __builtin_amdgcn_mfma_f32_16x16x32_bf16(a, bf, acc, 0, 0, 0);
        }
        // C/D: col=l15 -> t, row=lk*4+j -> position
        if (t < 18) {
            float bias = bp[t];
#pragma unroll
            for (int j = 0; j < 4; ++j)
                s_pm[t][lk * 4 + j] = acc[j] + bias;
        } else if (t < 27) {
            float bias = bm[t - 18];
#pragma unroll
            for (int j = 0; j < 4; ++j)
                s_pm[t][lk * 4 + j] = 1.f / (1.f + expf(-(acc[j] + bias)));
        }
    }
    __syncthreads();

    // ---- phase 1: sampling params (16 pos x 9 taps = 144) from s_pm ----
    if (tid < MPB * 9) {
        int k = tid >> 4;            // 0..8
        int p = tid & 15;
        int wo = wo0 + p;
        float dy = s_pm[2 * k][p];
        float dx = s_pm[2 * k + 1][p];
        float m  = s_pm[18 + k][p];
        float py = (float)(ho - 1 + k / 3) + dy;
        float px = (float)(wo - 1 + k % 3) + dx;
        float fy = floorf(py), fx = floorf(px);
        float ly = py - fy, lx = px - fx;
        int y0 = (int)fy, x0 = (int)fx;
        int y1 = y0 + 1, x1 = x0 + 1;
        float vy0 = ((unsigned)y0 < 64u) ? 1.f : 0.f;
        float vy1 = ((unsigned)y1 < 64u) ? 1.f : 0.f;
        float vx0 = ((unsigned)x0 < 64u) ? 1.f : 0.f;
        float vx1 = ((unsigned)x1 < 64u) ? 1.f : 0.f;
        int y0c = min(max(y0, 0), 63), y1c = min(max(y1, 0), 63);
        int x0c = min(max(x0, 0), 63), x1c = min(max(x1, 0), 63);
        int tt = p * 9 + k;
        s_yx[tt] = (unsigned)y0c | ((unsigned)y1c << 8) | ((unsigned)x0c << 16) | ((unsigned)x1c << 24);
        s_wh[tt * 4 + 0] = (_Float16)((1.f - ly) * (1.f - lx) * m * vy0 * vx0);
        s_wh[tt * 4 + 1] = (_Float16)((1.f - ly) * lx * m * vy0 * vx1);
        s_wh[tt * 4 + 2] = (_Float16)(ly * (1.f - lx) * m * vy1 * vx0);
        s_wh[tt * 4 + 3] = (_Float16)(ly * lx * m * vy1 * vx1);
    }
    __syncthreads();

    // ---- phase 2: gather; 8-lane groups, short8 (16B) corner loads ----
    {
        const int g  = tid >> 3;            // 0..31 groups
        const int li = tid & 7;
        const int c0 = li * 8;
#pragma unroll
        for (int it = 0; it < 5; ++it) {
            int pr = it * 32 + g;           // 0..159, guard at 144
            if (pr < MPB * 9) {
                unsigned yx = s_yx[pr];
                int y0 = yx & 255, y1 = (yx >> 8) & 255;
                int x0 = (yx >> 16) & 255, x1 = yx >> 24;
                float w0 = (float)s_wh[pr * 4 + 0], w1 = (float)s_wh[pr * 4 + 1];
                float w2 = (float)s_wh[pr * 4 + 2], w3 = (float)s_wh[pr * 4 + 3];
                short8 v00 = *(const short8*)&xb[(((y0 << 6) + x0) << 6) + c0];
                short8 v01 = *(const short8*)&xb[(((y0 << 6) + x1) << 6) + c0];
                short8 v10 = *(const short8*)&xb[(((y1 << 6) + x0) << 6) + c0];
                short8 v11 = *(const short8*)&xb[(((y1 << 6) + x1) << 6) + c0];
                int p = pr / 9, k = pr - p * 9;
                union { unsigned u[4]; short8 s; } pk;
#pragma unroll
                for (int h = 0; h < 4; ++h) {
                    float fa = w0 * bf2f(v00[2*h])   + w1 * bf2f(v01[2*h])
                             + w2 * bf2f(v10[2*h])   + w3 * bf2f(v11[2*h]);
                    float fb = w0 * bf2f(v00[2*h+1]) + w1 * bf2f(v01[2*h+1])
                             + w2 * bf2f(v10[2*h+1]) + w3 * bf2f(v11[2*h+1]);
                    pk.u[h] = cvt_pk_bf16(fa, fb);
                }
                *(short8*)&val[p * CKP + (k << 6) + c0] = pk.s;   // ds_write_b128
            }
        }
    }
    __syncthreads();

    // ---- phase 3: 4 waves; wave owns co = wv*32 .. wv*32+31 ----
    f32x4 acc0 = (f32x4)(0.f);
    f32x4 acc1 = (f32x4)(0.f);
    const short* wq0 = wt2 + (size_t)(wv * 32 + l15) * 32 + lk * 8;
    const short* wq1 = wq0 + 16 * 32;
    const int arow = l15 * CKP + lk * 8;
#pragma unroll
    for (int kc = 0; kc < 18; ++kc) {
        short8 a  = *(const short8*)&val[arow + kc * 32];
        short8 b0 = *(const short8*)&wq0[kc * 4096];
        short8 b1 = *(const short8*)&wq1[kc * 4096];
        acc0 = __builtin_amdgcn_mfma_f32_16x16x32_bf16(a, b0, acc0, 0, 0, 0);
        acc1 = __builtin_amdgcn_mfma_f32_16x16x32_bf16(a, b1, acc1, 0, 0, 0);
    }

    // ---- epilogue: y writes (+bias) and BN partials (64-slot spread) ----
    {
        int co0 = wv * 32 + l15;
        int co1 = co0 + 16;
        float bias0 = bd[co0], bias1 = bd[co1];
        float4 o;
        o.x = acc0[0] + bias0; o.y = acc0[1] + bias0;
        o.z = acc0[2] + bias0; o.w = acc0[3] + bias0;
        *(float4*)&y[((size_t)(b * COUT + co0)) * HW + ho * WW + wo0 + lk * 4] = o;
        o.x = acc1[0] + bias1; o.y = acc1[1] + bias1;
        o.z = acc1[2] + bias1; o.w = acc1[3] + bias1;
        *(float4*)&y[((size_t)(b * COUT + co1)) * HW + ho * WW + wo0 + lk * 4] = o;
    }
    float s0 = acc0[0] + acc0[1] + acc0[2] + acc0[3];
    float q0 = acc0[0]*acc0[0] + acc0[1]*acc0[1] + acc0[2]*acc0[2] + acc0[3]*acc0[3];
    float s1 = acc1[0] + acc1[1] + acc1[2] + acc1[3];
    float q1 = acc1[0]*acc1[0] + acc1[1]*acc1[1] + acc1[2]*acc1[2] + acc1[3]*acc1[3];
    s0 += __shfl_xor(s0, 16); s0 += __shfl_xor(s0, 32);
    q0 += __shfl_xor(q0, 16); q0 += __shfl_xor(q0, 32);
    s1 += __shfl_xor(s1, 16); s1 += __shfl_xor(s1, 32);
    q1 += __shfl_xor(q1, 16); q1 += __shfl_xor(q1, 32);
    if (lane < 16) {
        float* slot = gstat + (bid & 63) * 256;
        int co0 = wv * 32 + lane;
        atomicAdd(&slot[co0],            s0);
        atomicAdd(&slot[128 + co0],      q0);
        atomicAdd(&slot[co0 + 16],       s1);
        atomicAdd(&slot[128 + co0 + 16], q1);
    }
}

// ---------------------------------------------------------------------------
// Kernel 3: finalize BN scale/shift (reduce 64 slots)
__global__ __launch_bounds__(128) void k_finalize(const float* __restrict__ gstat,
                                                  const float* __restrict__ bd,
                                                  const float* __restrict__ gamma,
                                                  const float* __restrict__ beta,
                                                  float* __restrict__ sAB) {
    int c = threadIdx.x;
    float s = 0.f, q = 0.f;
    for (int sl = 0; sl < 64; ++sl) {
        s += gstat[sl * 256 + c];
        q += gstat[sl * 256 + 128 + c];
    }
    const float invN = 1.f / (float)(BB * HW);
    float mean_acc = s * invN;
    float var = q * invN - mean_acc * mean_acc;
    float mean_y = mean_acc + bd[c];
    float A = gamma[c] * rsqrtf(var + 1e-5f);
    sAB[c]       = A;
    sAB[128 + c] = beta[c] - mean_y * A;
}

// ---------------------------------------------------------------------------
// Kernel 4: normalize + exact GELU (in-place on d_out)
__global__ __launch_bounds__(256) void k_norm_gelu(float* __restrict__ y,
                                                   const float* __restrict__ sAB) {
    int i4 = blockIdx.x * 256 + threadIdx.x;
    if (i4 >= (BB * COUT * HW) / 4) return;
    int c = (i4 >> 10) & 127;
    float A  = sAB[c];
    float Bc = sAB[128 + c];
    float4 v = ((const float4*)y)[i4];
    float4 r;
    float t;
    t = v.x * A + Bc; r.x = 0.5f * t * (1.f + erff(t * 0.70710678118654752f));
    t = v.y * A + Bc; r.y = 0.5f * t * (1.f + erff(t * 0.70710678118654752f));
    t = v.z * A + Bc; r.z = 0.5f * t * (1.f + erff(t * 0.70710678118654752f));
    t = v.w * A + Bc; r.w = 0.5f * t * (1.f + erff(t * 0.70710678118654752f));
    ((float4*)y)[i4] = r;
}

// ---------------------------------------------------------------------------
extern "C" void kernel_launch(void* const* d_in, const int* in_sizes, int n_in,
                              void* d_out, int out_size, void* d_ws, size_t ws_size,
                              hipStream_t stream) {
    const float* x     = (const float*)d_in[0];
    const float* w_p   = (const float*)d_in[1];
    const float* b_p   = (const float*)d_in[2];
    const float* w_m   = (const float*)d_in[3];
    const float* b_m   = (const float*)d_in[4];
    const float* w_d   = (const float*)d_in[5];
    const float* b_d   = (const float*)d_in[6];
    const float* gamma = (const float*)d_in[7];
    const float* beta  = (const float*)d_in[8];
    float* ws  = (float*)d_ws;
    float* y   = (float*)d_out;

    short* wt2  = (short*)(ws + WT_OFF);
    short* wpm2 = (short*)(ws + WPM_OFF);
    short* xh   = (short*)(ws + XH_OFF);
    float* sAB  = ws + SAB_OFF;
    float* gstat= ws + STAT_OFF;

    hipMemsetAsync(gstat, 0, 64 * 256 * sizeof(float), stream);
    k_nhwc<<<dim3(1024), dim3(256), 0, stream>>>(x, xh);
    k_pack<<<dim3((18 * 128 * 32 + 18 * 32 * 32) / 256), dim3(256), 0, stream>>>(w_d, w_p, w_m, wt2, wpm2);
    k_deform<<<dim3(BB * HW / MPB), dim3(256), 0, stream>>>(xh, wt2, wpm2, b_p, b_m, b_d, y, gstat);
    k_finalize<<<dim3(1), dim3(128), 0, stream>>>(gstat, b_d, gamma, beta, sAB);
    k_norm_gelu<<<dim3((BB * COUT * HW / 4 + 255) / 256), dim3(256), 0, stream>>>(y, sAB);
}

// Round 13
// 89.896 us; speedup vs baseline: 1.2347x; 1.1808x over previous
//
#include <hip/hip_runtime.h>
#include <math.h>

#define BB 16
#define CIN 64
#define HH 64
#define WW 64
#define COUT 128
#define HW 4096          // HH*WW
#define CK 576           // CIN*9
#define CKP 584          // LDS stride (shorts) for val

typedef __attribute__((ext_vector_type(8))) short short8;
typedef __attribute__((ext_vector_type(4))) float f32x4;

// ---- workspace layout (float indices) ----
#define WT_OFF    0                         // wt2: 18*128*32 shorts = 36864 floats
#define WPM_OFF   36864                     // wpm2: 18*32*32 shorts = 9216 floats
#define XH_OFF    46080                     // B*HW*CIN shorts = 8388608 floats
#define SAB_OFF   8434688                   // 256 floats
#define STAT_OFF  8434944                   // 64 slots * 256 floats = 16384

__device__ __forceinline__ short f2bf(float f) {
    union { float f; unsigned u; } cv; cv.f = f;
    unsigned u = cv.u;
    unsigned r = (u + 0x7fffu + ((u >> 16) & 1u)) >> 16;
    return (short)r;
}
__device__ __forceinline__ float bf2f(short s) {
    union { unsigned u; float f; } cv;
    cv.u = ((unsigned)(unsigned short)s) << 16;
    return cv.f;
}
__device__ __forceinline__ unsigned cvt_pk_bf16(float lo, float hi) {
    unsigned r;
    asm("v_cvt_pk_bf16_f32 %0, %1, %2" : "=v"(r) : "v"(lo), "v"(hi));
    return r;
}

// ---------------------------------------------------------------------------
// Kernel A: transpose x NCHW -> NHWC bf16 (xh[b][y][x][c])
__global__ __launch_bounds__(256) void k_nhwc(const float* __restrict__ x,
                                              short* __restrict__ xh) {
    __shared__ float t[64][65];
    const int blk  = blockIdx.x;
    const int b    = blk >> 6;
    const int pos0 = (blk & 63) << 6;
    const int a    = threadIdx.x & 63;
    const int q    = threadIdx.x >> 6;
#pragma unroll
    for (int i = 0; i < 16; ++i) {
        int c = i * 4 + q;
        t[c][a] = x[((size_t)(b * CIN + c)) * HW + pos0 + a];
    }
    __syncthreads();
#pragma unroll
    for (int i = 0; i < 16; ++i) {
        int p = i * 4 + q;
        xh[((size_t)b * HW + pos0 + p) * CIN + a] = f2bf(t[a][p]);
    }
}

// ---------------------------------------------------------------------------
// Kernel B: pack weights to bf16, K-MAJOR panels.
__global__ __launch_bounds__(256) void k_pack(const float* __restrict__ wd,
                                              const float* __restrict__ wp,
                                              const float* __restrict__ wm,
                                              short* __restrict__ wt2,
                                              short* __restrict__ wpm2) {
    int i = blockIdx.x * 256 + threadIdx.x;
    if (i < 18 * 128 * 32) {
        int kc  = i >> 12;
        int rem = i & 4095;
        int co  = rem >> 5;
        int kl  = rem & 31;
        int kk  = kc * 32 + kl;
        int k   = kk >> 6;
        int c   = kk & 63;
        wt2[i] = f2bf(wd[co * CK + c * 9 + k]);
        return;
    }
    i -= 18 * 128 * 32;
    if (i < 18 * 32 * 32) {
        int kc  = i >> 10;
        int rem = i & 1023;
        int t   = rem >> 5;
        int kl  = rem & 31;
        int kk  = kc * 32 + kl;
        int k   = kk >> 6;
        int c   = kk & 63;
        float v = 0.f;
        if (t < 18)      v = wp[t * CK + c * 9 + k];
        else if (t < 27) v = wm[(t - 18) * CK + c * 9 + k];
        wpm2[i] = f2bf(v);
    }
}

// ---------------------------------------------------------------------------
// conv A-fragment loader (shifted-window NHWC patch)
__device__ __forceinline__ short8 conv_a(const short* __restrict__ xb,
                                         int ho, int wo, int lk, int kc) {
    const int k  = kc >> 1;
    const int c0 = (kc & 1) * 32 + lk * 8;
    const int yy = ho - 1 + k / 3;
    const int xx = wo - 1 + k % 3;
    const bool valid = ((unsigned)yy < 64u) & ((unsigned)xx < 64u);
    const int yyc = min(max(yy, 0), 63);
    const int xxc = min(max(xx, 0), 63);
    short8 a = *(const short8*)&xb[(((yyc << 6) + xxc) << 6) + c0];
    if (!valid) a = (short8)0;
    return a;
}

// ---------------------------------------------------------------------------
// Kernel 2: FUSED conv + deform + BN partials. MPB=32, 512 threads (8 waves).
//  phase 0: ALL 8 waves: (mw pos-half, nw ch-half, kh K-half), 9 MFMAs each
//           -> partial sums s_pm2[kh][t][p]
//  phase 1: params from s_pm2 (sum halves + bias)
//  phase 2: gather, 64 groups x 8 lanes, short8 corners
//  phase 3: wave owns 16 co -> B read ONCE per block, 2 MFMAs/kc
//  epilogue: y stores + 2 atomics/lane (64-slot spread)
#define MPB 32
__global__ __launch_bounds__(512) void k_deform(const short* __restrict__ xh,
                                                const short* __restrict__ wt2,
                                                const short* __restrict__ wpm2,
                                                const float* __restrict__ bp,
                                                const float* __restrict__ bm,
                                                const float* __restrict__ bd,
                                                float* __restrict__ y,
                                                float* __restrict__ gstat) {
    __shared__ short     val[MPB * CKP];     // 37376 B
    __shared__ float     s_pm2[2][32][MPB];  // 8192 B  conv partials [kh][t][p]
    __shared__ unsigned  s_yx[MPB * 9];      // 1152 B
    __shared__ _Float16  s_wh[MPB * 9 * 4];  // 2304 B  -> 49024 B total

    const int bid  = blockIdx.x;                       // 2048
    const int swz  = (bid & 7) * 256 + (bid >> 3);     // XCD-chunked
    const int pos0 = swz * MPB;
    const int b   = pos0 >> 12;
    const int ho  = (pos0 >> 6) & 63;
    const int wo0 = pos0 & 63;                         // 0 or 32
    const int tid = threadIdx.x;
    const int wv   = tid >> 6;
    const int lane = tid & 63;
    const int l15  = lane & 15;
    const int lk   = lane >> 4;

    const short* xb = xh + (size_t)b * HW * CIN;

    // ---- phase 0: offset/mask conv, all 8 waves, K-split ----
    {
        const int mw = wv & 1;          // position half
        const int nw = (wv >> 1) & 1;   // channel half
        const int kh = wv >> 2;         // K half
        const int t  = nw * 16 + l15;   // out channel 0..31 (>=27 uses zero rows)
        const short* wr = wpm2 + t * 32 + lk * 8;
        const int wo = wo0 + mw * 16 + l15;
        f32x4 acc = (f32x4)(0.f);
#pragma unroll
        for (int kc = kh * 9; kc < kh * 9 + 9; ++kc) {
            short8 a  = conv_a(xb, ho, wo, lk, kc);
            short8 bf = *(const short8*)&wr[kc * 1024];
            acc = __builtin_amdgcn_mfma_f32_16x16x32_bf16(a, bf, acc, 0, 0, 0);
        }
        // C/D: col=l15 -> t, row=lk*4+j -> local position
#pragma unroll
        for (int j = 0; j < 4; ++j)
            s_pm2[kh][t][mw * 16 + lk * 4 + j] = acc[j];
    }
    __syncthreads();

    // ---- phase 1: sampling params (32 pos x 9 taps = 288) ----
    if (tid < MPB * 9) {
        int k = tid >> 5;               // 0..8
        int p = tid & 31;
        int wo = wo0 + p;
        float dy = s_pm2[0][2 * k    ][p] + s_pm2[1][2 * k    ][p] + bp[2 * k];
        float dx = s_pm2[0][2 * k + 1][p] + s_pm2[1][2 * k + 1][p] + bp[2 * k + 1];
        float mm = s_pm2[0][18 + k   ][p] + s_pm2[1][18 + k   ][p] + bm[k];
        float m  = 1.f / (1.f + expf(-mm));
        float py = (float)(ho - 1 + k / 3) + dy;
        float px = (float)(wo - 1 + k % 3) + dx;
        float fy = floorf(py), fx = floorf(px);
        float ly = py - fy, lx = px - fx;
        int y0 = (int)fy, x0 = (int)fx;
        int y1 = y0 + 1, x1 = x0 + 1;
        float vy0 = ((unsigned)y0 < 64u) ? 1.f : 0.f;
        float vy1 = ((unsigned)y1 < 64u) ? 1.f : 0.f;
        float vx0 = ((unsigned)x0 < 64u) ? 1.f : 0.f;
        float vx1 = ((unsigned)x1 < 64u) ? 1.f : 0.f;
        int y0c = min(max(y0, 0), 63), y1c = min(max(y1, 0), 63);
        int x0c = min(max(x0, 0), 63), x1c = min(max(x1, 0), 63);
        int tt = p * 9 + k;
        s_yx[tt] = (unsigned)y0c | ((unsigned)y1c << 8) | ((unsigned)x0c << 16) | ((unsigned)x1c << 24);
        s_wh[tt * 4 + 0] = (_Float16)((1.f - ly) * (1.f - lx) * m * vy0 * vx0);
        s_wh[tt * 4 + 1] = (_Float16)((1.f - ly) * lx * m * vy0 * vx1);
        s_wh[tt * 4 + 2] = (_Float16)(ly * (1.f - lx) * m * vy1 * vx0);
        s_wh[tt * 4 + 3] = (_Float16)(ly * lx * m * vy1 * vx1);
    }
    __syncthreads();

    // ---- phase 2: gather; 64 groups x 8 lanes, short8 (16B) corners ----
    {
        const int g  = tid >> 3;        // 0..63 groups
        const int li = tid & 7;
        const int c0 = li * 8;
#pragma unroll
        for (int it = 0; it < 5; ++it) {
            int pr = it * 64 + g;       // 0..319, guard 288
            if (pr < MPB * 9) {
                unsigned yx = s_yx[pr];
                int y0 = yx & 255, y1 = (yx >> 8) & 255;
                int x0 = (yx >> 16) & 255, x1 = yx >> 24;
                float w0 = (float)s_wh[pr * 4 + 0], w1 = (float)s_wh[pr * 4 + 1];
                float w2 = (float)s_wh[pr * 4 + 2], w3 = (float)s_wh[pr * 4 + 3];
                short8 v00 = *(const short8*)&xb[(((y0 << 6) + x0) << 6) + c0];
                short8 v01 = *(const short8*)&xb[(((y0 << 6) + x1) << 6) + c0];
                short8 v10 = *(const short8*)&xb[(((y1 << 6) + x0) << 6) + c0];
                short8 v11 = *(const short8*)&xb[(((y1 << 6) + x1) << 6) + c0];
                int p = pr / 9, k = pr - p * 9;
                union { unsigned u[4]; short8 s; } pk;
#pragma unroll
                for (int h = 0; h < 4; ++h) {
                    float fa = w0 * bf2f(v00[2*h])   + w1 * bf2f(v01[2*h])
                             + w2 * bf2f(v10[2*h])   + w3 * bf2f(v11[2*h]);
                    float fb = w0 * bf2f(v00[2*h+1]) + w1 * bf2f(v01[2*h+1])
                             + w2 * bf2f(v10[2*h+1]) + w3 * bf2f(v11[2*h+1]);
                    pk.u[h] = cvt_pk_bf16(fa, fb);
                }
                *(short8*)&val[p * CKP + (k << 6) + c0] = pk.s;   // ds_write_b128
            }
        }
    }
    __syncthreads();

    // ---- phase 3: wave owns co = wv*16..+15; B read once per block ----
    f32x4 acc0 = (f32x4)(0.f);      // positions 0..15
    f32x4 acc1 = (f32x4)(0.f);      // positions 16..31
    const short* wq = wt2 + (size_t)(wv * 16 + l15) * 32 + lk * 8;
    const int arow = l15 * CKP + lk * 8;
#pragma unroll
    for (int kc = 0; kc < 18; ++kc) {
        short8 a0 = *(const short8*)&val[arow + kc * 32];
        short8 a1 = *(const short8*)&val[arow + 16 * CKP + kc * 32];
        short8 bf = *(const short8*)&wq[kc * 4096];
        acc0 = __builtin_amdgcn_mfma_f32_16x16x32_bf16(a0, bf, acc0, 0, 0, 0);
        acc1 = __builtin_amdgcn_mfma_f32_16x16x32_bf16(a1, bf, acc1, 0, 0, 0);
    }

    // ---- epilogue: y writes (+bias) and BN partials (64-slot spread) ----
    const int co = wv * 16 + l15;
    {
        float bias = bd[co];
        float4 o;
        o.x = acc0[0] + bias; o.y = acc0[1] + bias;
        o.z = acc0[2] + bias; o.w = acc0[3] + bias;
        *(float4*)&y[((size_t)(b * COUT + co)) * HW + ho * WW + wo0 + lk * 4] = o;
        o.x = acc1[0] + bias; o.y = acc1[1] + bias;
        o.z = acc1[2] + bias; o.w = acc1[3] + bias;
        *(float4*)&y[((size_t)(b * COUT + co)) * HW + ho * WW + wo0 + 16 + lk * 4] = o;
    }
    float s0 = acc0[0] + acc0[1] + acc0[2] + acc0[3]
             + acc1[0] + acc1[1] + acc1[2] + acc1[3];
    float q0 = acc0[0]*acc0[0] + acc0[1]*acc0[1] + acc0[2]*acc0[2] + acc0[3]*acc0[3]
             + acc1[0]*acc1[0] + acc1[1]*acc1[1] + acc1[2]*acc1[2] + acc1[3]*acc1[3];
    s0 += __shfl_xor(s0, 16); s0 += __shfl_xor(s0, 32);
    q0 += __shfl_xor(q0, 16); q0 += __shfl_xor(q0, 32);
    if (lane < 16) {
        float* slot = gstat + (bid & 63) * 256;
        atomicAdd(&slot[wv * 16 + lane],       s0);
        atomicAdd(&slot[128 + wv * 16 + lane], q0);
    }
}

// ---------------------------------------------------------------------------
// Kernel 3: finalize BN scale/shift (reduce 64 slots)
__global__ __launch_bounds__(128) void k_finalize(const float* __restrict__ gstat,
                                                  const float* __restrict__ bd,
                                                  const float* __restrict__ gamma,
                                                  const float* __restrict__ beta,
                                                  float* __restrict__ sAB) {
    int c = threadIdx.x;
    float s = 0.f, q = 0.f;
    for (int sl = 0; sl < 64; ++sl) {
        s += gstat[sl * 256 + c];
        q += gstat[sl * 256 + 128 + c];
    }
    const float invN = 1.f / (float)(BB * HW);
    float mean_acc = s * invN;
    float var = q * invN - mean_acc * mean_acc;
    float mean_y = mean_acc + bd[c];
    float A = gamma[c] * rsqrtf(var + 1e-5f);
    sAB[c]       = A;
    sAB[128 + c] = beta[c] - mean_y * A;
}

// ---------------------------------------------------------------------------
// Kernel 4: normalize + exact GELU (in-place on d_out)
__global__ __launch_bounds__(256) void k_norm_gelu(float* __restrict__ y,
                                                   const float* __restrict__ sAB) {
    int i4 = blockIdx.x * 256 + threadIdx.x;
    if (i4 >= (BB * COUT * HW) / 4) return;
    int c = (i4 >> 10) & 127;
    float A  = sAB[c];
    float Bc = sAB[128 + c];
    float4 v = ((const float4*)y)[i4];
    float4 r;
    float t;
    t = v.x * A + Bc; r.x = 0.5f * t * (1.f + erff(t * 0.70710678118654752f));
    t = v.y * A + Bc; r.y = 0.5f * t * (1.f + erff(t * 0.70710678118654752f));
    t = v.z * A + Bc; r.z = 0.5f * t * (1.f + erff(t * 0.70710678118654752f));
    t = v.w * A + Bc; r.w = 0.5f * t * (1.f + erff(t * 0.70710678118654752f));
    ((float4*)y)[i4] = r;
}

// ---------------------------------------------------------------------------
extern "C" void kernel_launch(void* const* d_in, const int* in_sizes, int n_in,
                              void* d_out, int out_size, void* d_ws, size_t ws_size,
                              hipStream_t stream) {
    const float* x     = (const float*)d_in[0];
    const float* w_p   = (const float*)d_in[1];
    const float* b_p   = (const float*)d_in[2];
    const float* w_m   = (const float*)d_in[3];
    const float* b_m   = (const float*)d_in[4];
    const float* w_d   = (const float*)d_in[5];
    const float* b_d   = (const float*)d_in[6];
    const float* gamma = (const float*)d_in[7];
    const float* beta  = (const float*)d_in[8];
    float* ws  = (float*)d_ws;
    float* y   = (float*)d_out;

    short* wt2  = (short*)(ws + WT_OFF);
    short* wpm2 = (short*)(ws + WPM_OFF);
    short* xh   = (short*)(ws + XH_OFF);
    float* sAB  = ws + SAB_OFF;
    float* gstat= ws + STAT_OFF;

    hipMemsetAsync(gstat, 0, 64 * 256 * sizeof(float), stream);
    k_nhwc<<<dim3(1024), dim3(256), 0, stream>>>(x, xh);
    k_pack<<<dim3((18 * 128 * 32 + 18 * 32 * 32) / 256), dim3(256), 0, stream>>>(w_d, w_p, w_m, wt2, wpm2);
    k_deform<<<dim3(BB * HW / MPB), dim3(512), 0, stream>>>(xh, wt2, wpm2, b_p, b_m, b_d, y, gstat);
    k_finalize<<<dim3(1), dim3(128), 0, stream>>>(gstat, b_d, gamma, beta, sAB);
    k_norm_gelu<<<dim3((BB * COUT * HW / 4 + 255) / 256), dim3(256), 0, stream>>>(y, sAB);
}

// Round 14
// 86.454 us; speedup vs baseline: 1.2839x; 1.0398x over previous
//
#include <hip/hip_runtime.h>
#include <math.h>

#define BB 16
#define CIN 64
#define HH 64
#define WW 64
#define COUT 128
#define HW 4096          // HH*WW
#define CK 576           // CIN*9
#define VROW 612         // val row stride (shorts): 9 taps * 68 (64 + 4 pad)

typedef __attribute__((ext_vector_type(8))) short short8;
typedef __attribute__((ext_vector_type(4))) short short4v;
typedef __attribute__((ext_vector_type(4))) float f32x4;

// ---- workspace layout (float indices) ----
#define WT_OFF    0                         // wt2: 73728 shorts = 36864 floats
#define WPM_OFF   36864                     // wpm2: 18432 shorts = 9216 floats
#define XH_OFF    46080                     // xh: 4194304 shorts = 2097152 floats
#define YB_OFF    2143232                   // yb: 8388608 shorts = 4194304 floats
#define SAB_OFF   6337536                   // 256 floats
#define STAT_OFF  6337792                   // 64 slots * 256 floats

__device__ __forceinline__ short f2bf(float f) {
    union { float f; unsigned u; } cv; cv.f = f;
    unsigned u = cv.u;
    unsigned r = (u + 0x7fffu + ((u >> 16) & 1u)) >> 16;
    return (short)r;
}
__device__ __forceinline__ float bf2f(short s) {
    union { unsigned u; float f; } cv;
    cv.u = ((unsigned)(unsigned short)s) << 16;
    return cv.f;
}
__device__ __forceinline__ unsigned cvt_pk_bf16(float lo, float hi) {
    unsigned r;
    asm("v_cvt_pk_bf16_f32 %0, %1, %2" : "=v"(r) : "v"(lo), "v"(hi));
    return r;
}

// ---------------------------------------------------------------------------
// Kernel A: FUSED  (blocks <1024) x NCHW -> NHWC bf16  |  (blocks >=1024) weight pack
__global__ __launch_bounds__(256) void k_prep(const float* __restrict__ x,
                                              const float* __restrict__ wd,
                                              const float* __restrict__ wp,
                                              const float* __restrict__ wm,
                                              short* __restrict__ xh,
                                              short* __restrict__ wt2,
                                              short* __restrict__ wpm2) {
    const int blk = blockIdx.x;
    if (blk < 1024) {
        __shared__ float t[64][65];
        const int b    = blk >> 6;
        const int pos0 = (blk & 63) << 6;
        const int a    = threadIdx.x & 63;
        const int q    = threadIdx.x >> 6;
#pragma unroll
        for (int i = 0; i < 16; ++i) {
            int c = i * 4 + q;
            t[c][a] = x[((size_t)(b * CIN + c)) * HW + pos0 + a];
        }
        __syncthreads();
#pragma unroll
        for (int i = 0; i < 16; ++i) {
            int p = i * 4 + q;
            xh[((size_t)b * HW + pos0 + p) * CIN + a] = f2bf(t[a][p]);
        }
        return;
    }
    int i = (blk - 1024) * 256 + threadIdx.x;       // 360 blocks * 256 = 92160
    if (i < 18 * 128 * 32) {
        int kc  = i >> 12;
        int rem = i & 4095;
        int co  = rem >> 5;
        int kl  = rem & 31;
        int kk  = kc * 32 + kl;
        int k   = kk >> 6;
        int c   = kk & 63;
        wt2[i] = f2bf(wd[co * CK + c * 9 + k]);
        return;
    }
    i -= 18 * 128 * 32;
    if (i < 18 * 32 * 32) {
        int kc  = i >> 10;
        int rem = i & 1023;
        int t   = rem >> 5;
        int kl  = rem & 31;
        int kk  = kc * 32 + kl;
        int k   = kk >> 6;
        int c   = kk & 63;
        float v = 0.f;
        if (t < 18)      v = wp[t * CK + c * 9 + k];
        else if (t < 27) v = wm[(t - 18) * CK + c * 9 + k];
        wpm2[i] = f2bf(v);
    }
}

// ---------------------------------------------------------------------------
// conv A-fragment loader (shifted-window NHWC patch)
__device__ __forceinline__ short8 conv_a(const short* __restrict__ xb,
                                         int ho, int wo, int lk, int kc) {
    const int k  = kc >> 1;
    const int c0 = (kc & 1) * 32 + lk * 8;
    const int yy = ho - 1 + k / 3;
    const int xx = wo - 1 + k % 3;
    const bool valid = ((unsigned)yy < 64u) & ((unsigned)xx < 64u);
    const int yyc = min(max(yy, 0), 63);
    const int xxc = min(max(xx, 0), 63);
    short8 a = *(const short8*)&xb[(((yyc << 6) + xxc) << 6) + c0];
    if (!valid) a = (short8)0;
    return a;
}

// ---------------------------------------------------------------------------
// Kernel 2: FUSED conv + deform + BN partials. MPB=32, 512 threads (8 waves).
// Conflict-fixed LDS: s_pm2 padded [33], val padded per-tap 68.
// y stored as bf16.
#define MPB 32
__global__ __launch_bounds__(512) void k_deform(const short* __restrict__ xh,
                                                const short* __restrict__ wt2,
                                                const short* __restrict__ wpm2,
                                                const float* __restrict__ bp,
                                                const float* __restrict__ bm,
                                                const float* __restrict__ bd,
                                                short* __restrict__ yb,
                                                float* __restrict__ gstat) {
    __shared__ short     val[MPB * VROW];    // 39168 B  [p][k*68 + c]
    __shared__ float     s_pm2[2][32][33];   // 8448 B   conv partials [kh][t][p]
    __shared__ unsigned  s_yx[MPB * 9];      // 1152 B
    __shared__ _Float16  s_wh[MPB * 9 * 4];  // 2304 B   -> 51072 B total

    const int bid  = blockIdx.x;                       // 2048
    const int swz  = (bid & 7) * 256 + (bid >> 3);     // XCD-chunked
    const int pos0 = swz * MPB;
    const int b   = pos0 >> 12;
    const int ho  = (pos0 >> 6) & 63;
    const int wo0 = pos0 & 63;                         // 0 or 32
    const int tid = threadIdx.x;
    const int wv   = tid >> 6;
    const int lane = tid & 63;
    const int l15  = lane & 15;
    const int lk   = lane >> 4;

    const short* xb = xh + (size_t)b * HW * CIN;

    // ---- phase 0: offset/mask conv, all 8 waves, K-split ----
    {
        const int mw = wv & 1;          // position half
        const int nw = (wv >> 1) & 1;   // channel half
        const int kh = wv >> 2;         // K half
        const int t  = nw * 16 + l15;   // out channel 0..31 (>=27 uses zero rows)
        const short* wr = wpm2 + t * 32 + lk * 8;
        const int wo = wo0 + mw * 16 + l15;
        f32x4 acc = (f32x4)(0.f);
#pragma unroll
        for (int kc = kh * 9; kc < kh * 9 + 9; ++kc) {
            short8 a  = conv_a(xb, ho, wo, lk, kc);
            short8 bf = *(const short8*)&wr[kc * 1024];
            acc = __builtin_amdgcn_mfma_f32_16x16x32_bf16(a, bf, acc, 0, 0, 0);
        }
#pragma unroll
        for (int j = 0; j < 4; ++j)
            s_pm2[kh][t][mw * 16 + lk * 4 + j] = acc[j];
    }
    __syncthreads();

    // ---- phase 1: sampling params (32 pos x 9 taps = 288) ----
    if (tid < MPB * 9) {
        int k = tid >> 5;               // 0..8
        int p = tid & 31;
        int wo = wo0 + p;
        float dy = s_pm2[0][2 * k    ][p] + s_pm2[1][2 * k    ][p] + bp[2 * k];
        float dx = s_pm2[0][2 * k + 1][p] + s_pm2[1][2 * k + 1][p] + bp[2 * k + 1];
        float mm = s_pm2[0][18 + k   ][p] + s_pm2[1][18 + k   ][p] + bm[k];
        float m  = 1.f / (1.f + expf(-mm));
        float py = (float)(ho - 1 + k / 3) + dy;
        float px = (float)(wo - 1 + k % 3) + dx;
        float fy = floorf(py), fx = floorf(px);
        float ly = py - fy, lx = px - fx;
        int y0 = (int)fy, x0 = (int)fx;
        int y1 = y0 + 1, x1 = x0 + 1;
        float vy0 = ((unsigned)y0 < 64u) ? 1.f : 0.f;
        float vy1 = ((unsigned)y1 < 64u) ? 1.f : 0.f;
        float vx0 = ((unsigned)x0 < 64u) ? 1.f : 0.f;
        float vx1 = ((unsigned)x1 < 64u) ? 1.f : 0.f;
        int y0c = min(max(y0, 0), 63), y1c = min(max(y1, 0), 63);
        int x0c = min(max(x0, 0), 63), x1c = min(max(x1, 0), 63);
        int tt = p * 9 + k;
        s_yx[tt] = (unsigned)y0c | ((unsigned)y1c << 8) | ((unsigned)x0c << 16) | ((unsigned)x1c << 24);
        s_wh[tt * 4 + 0] = (_Float16)((1.f - ly) * (1.f - lx) * m * vy0 * vx0);
        s_wh[tt * 4 + 1] = (_Float16)((1.f - ly) * lx * m * vy0 * vx1);
        s_wh[tt * 4 + 2] = (_Float16)(ly * (1.f - lx) * m * vy1 * vx0);
        s_wh[tt * 4 + 3] = (_Float16)(ly * lx * m * vy1 * vx1);
    }
    __syncthreads();

    // ---- phase 2: gather; 64 groups x 8 lanes, short8 (16B) corners ----
    {
        const int g  = tid >> 3;        // 0..63 groups
        const int li = tid & 7;
        const int c0 = li * 8;
#pragma unroll
        for (int it = 0; it < 5; ++it) {
            int pr = it * 64 + g;       // 0..319, guard 288
            if (pr < MPB * 9) {
                unsigned yx = s_yx[pr];
                int y0 = yx & 255, y1 = (yx >> 8) & 255;
                int x0 = (yx >> 16) & 255, x1 = yx >> 24;
                float w0 = (float)s_wh[pr * 4 + 0], w1 = (float)s_wh[pr * 4 + 1];
                float w2 = (float)s_wh[pr * 4 + 2], w3 = (float)s_wh[pr * 4 + 3];
                short8 v00 = *(const short8*)&xb[(((y0 << 6) + x0) << 6) + c0];
                short8 v01 = *(const short8*)&xb[(((y0 << 6) + x1) << 6) + c0];
                short8 v10 = *(const short8*)&xb[(((y1 << 6) + x0) << 6) + c0];
                short8 v11 = *(const short8*)&xb[(((y1 << 6) + x1) << 6) + c0];
                int p = pr / 9, k = pr - p * 9;
                union { unsigned u[4]; short8 s; } pk;
#pragma unroll
                for (int h = 0; h < 4; ++h) {
                    float fa = w0 * bf2f(v00[2*h])   + w1 * bf2f(v01[2*h])
                             + w2 * bf2f(v10[2*h])   + w3 * bf2f(v11[2*h]);
                    float fb = w0 * bf2f(v00[2*h+1]) + w1 * bf2f(v01[2*h+1])
                             + w2 * bf2f(v10[2*h+1]) + w3 * bf2f(v11[2*h+1]);
                    pk.u[h] = cvt_pk_bf16(fa, fb);
                }
                *(short8*)&val[p * VROW + k * 68 + c0] = pk.s;   // ds_write_b128
            }
        }
    }
    __syncthreads();

    // ---- phase 3: wave owns co = wv*16..+15; B read once per block ----
    f32x4 acc0 = (f32x4)(0.f);      // positions 0..15
    f32x4 acc1 = (f32x4)(0.f);      // positions 16..31
    const short* wq = wt2 + (size_t)(wv * 16 + l15) * 32 + lk * 8;
    const int arow0 = l15 * VROW + lk * 8;
    const int arow1 = (l15 + 16) * VROW + lk * 8;
#pragma unroll
    for (int kc = 0; kc < 18; ++kc) {
        const int koff = (kc >> 1) * 68 + (kc & 1) * 32;
        short8 a0 = *(const short8*)&val[arow0 + koff];
        short8 a1 = *(const short8*)&val[arow1 + koff];
        short8 bf = *(const short8*)&wq[kc * 4096];
        acc0 = __builtin_amdgcn_mfma_f32_16x16x32_bf16(a0, bf, acc0, 0, 0, 0);
        acc1 = __builtin_amdgcn_mfma_f32_16x16x32_bf16(a1, bf, acc1, 0, 0, 0);
    }

    // ---- epilogue: bf16 y writes (+bias) and BN partials (64-slot spread) ----
    const int co = wv * 16 + l15;
    {
        float bias = bd[co];
        short* ybp = yb + ((size_t)(b * COUT + co)) * HW + ho * WW + wo0;
        union { unsigned u[2]; short4v s; } o0, o1;
        o0.u[0] = cvt_pk_bf16(acc0[0] + bias, acc0[1] + bias);
        o0.u[1] = cvt_pk_bf16(acc0[2] + bias, acc0[3] + bias);
        *(short4v*)&ybp[lk * 4] = o0.s;
        o1.u[0] = cvt_pk_bf16(acc1[0] + bias, acc1[1] + bias);
        o1.u[1] = cvt_pk_bf16(acc1[2] + bias, acc1[3] + bias);
        *(short4v*)&ybp[16 + lk * 4] = o1.s;
    }
    float s0 = acc0[0] + acc0[1] + acc0[2] + acc0[3]
             + acc1[0] + acc1[1] + acc1[2] + acc1[3];
    float q0 = acc0[0]*acc0[0] + acc0[1]*acc0[1] + acc0[2]*acc0[2] + acc0[3]*acc0[3]
             + acc1[0]*acc1[0] + acc1[1]*acc1[1] + acc1[2]*acc1[2] + acc1[3]*acc1[3];
    s0 += __shfl_xor(s0, 16); s0 += __shfl_xor(s0, 32);
    q0 += __shfl_xor(q0, 16); q0 += __shfl_xor(q0, 32);
    if (lane < 16) {
        float* slot = gstat + (bid & 63) * 256;
        atomicAdd(&slot[wv * 16 + lane],       s0);
        atomicAdd(&slot[128 + wv * 16 + lane], q0);
    }
}

// ---------------------------------------------------------------------------
// Kernel 3: finalize BN scale/shift (reduce 64 slots)
__global__ __launch_bounds__(128) void k_finalize(const float* __restrict__ gstat,
                                                  const float* __restrict__ bd,
                                                  const float* __restrict__ gamma,
                                                  const float* __restrict__ beta,
                                                  float* __restrict__ sAB) {
    int c = threadIdx.x;
    float s = 0.f, q = 0.f;
    for (int sl = 0; sl < 64; ++sl) {
        s += gstat[sl * 256 + c];
        q += gstat[sl * 256 + 128 + c];
    }
    const float invN = 1.f / (float)(BB * HW);
    float mean_acc = s * invN;
    float var = q * invN - mean_acc * mean_acc;
    float mean_y = mean_acc + bd[c];
    float A = gamma[c] * rsqrtf(var + 1e-5f);
    sAB[c]       = A;
    sAB[128 + c] = beta[c] - mean_y * A;
}

// ---------------------------------------------------------------------------
// Kernel 4: normalize + exact GELU. Reads bf16 y (16B/lane), writes f32 d_out.
__global__ __launch_bounds__(256) void k_norm_gelu(const short* __restrict__ yb,
                                                   const float* __restrict__ sAB,
                                                   float* __restrict__ out) {
    int i8 = blockIdx.x * 256 + threadIdx.x;        // 1048576 groups of 8
    if (i8 >= (BB * COUT * HW) / 8) return;
    int c = (i8 >> 9) & 127;
    float A  = sAB[c];
    float Bc = sAB[128 + c];
    short8 v = *(const short8*)&yb[(size_t)i8 * 8];
    float4 r0, r1;
    float t;
    t = bf2f(v[0]) * A + Bc; r0.x = 0.5f * t * (1.f + erff(t * 0.70710678118654752f));
    t = bf2f(v[1]) * A + Bc; r0.y = 0.5f * t * (1.f + erff(t * 0.70710678118654752f));
    t = bf2f(v[2]) * A + Bc; r0.z = 0.5f * t * (1.f + erff(t * 0.70710678118654752f));
    t = bf2f(v[3]) * A + Bc; r0.w = 0.5f * t * (1.f + erff(t * 0.70710678118654752f));
    t = bf2f(v[4]) * A + Bc; r1.x = 0.5f * t * (1.f + erff(t * 0.70710678118654752f));
    t = bf2f(v[5]) * A + Bc; r1.y = 0.5f * t * (1.f + erff(t * 0.70710678118654752f));
    t = bf2f(v[6]) * A + Bc; r1.z = 0.5f * t * (1.f + erff(t * 0.70710678118654752f));
    t = bf2f(v[7]) * A + Bc; r1.w = 0.5f * t * (1.f + erff(t * 0.70710678118654752f));
    *(float4*)&out[(size_t)i8 * 8]     = r0;
    *(float4*)&out[(size_t)i8 * 8 + 4] = r1;
}

// ---------------------------------------------------------------------------
extern "C" void kernel_launch(void* const* d_in, const int* in_sizes, int n_in,
                              void* d_out, int out_size, void* d_ws, size_t ws_size,
                              hipStream_t stream) {
    const float* x     = (const float*)d_in[0];
    const float* w_p   = (const float*)d_in[1];
    const float* b_p   = (const float*)d_in[2];
    const float* w_m   = (const float*)d_in[3];
    const float* b_m   = (const float*)d_in[4];
    const float* w_d   = (const float*)d_in[5];
    const float* b_d   = (const float*)d_in[6];
    const float* gamma = (const float*)d_in[7];
    const float* beta  = (const float*)d_in[8];
    float* ws  = (float*)d_ws;
    float* out = (float*)d_out;

    short* wt2  = (short*)(ws + WT_OFF);
    short* wpm2 = (short*)(ws + WPM_OFF);
    short* xh   = (short*)(ws + XH_OFF);
    short* yb   = (short*)(ws + YB_OFF);
    float* sAB  = ws + SAB_OFF;
    float* gstat= ws + STAT_OFF;

    hipMemsetAsync(gstat, 0, 64 * 256 * sizeof(float), stream);
    k_prep<<<dim3(1024 + 360), dim3(256), 0, stream>>>(x, w_d, w_p, w_m, xh, wt2, wpm2);
    k_deform<<<dim3(BB * HW / MPB), dim3(512), 0, stream>>>(xh, wt2, wpm2, b_p, b_m, b_d, yb, gstat);
    k_finalize<<<dim3(1), dim3(128), 0, stream>>>(gstat, b_d, gamma, beta, sAB);
    k_norm_gelu<<<dim3(BB * COUT * HW / 8 / 256), dim3(256), 0, stream>>>(yb, sAB, out);
}

// Round 15
// 84.495 us; speedup vs baseline: 1.3136x; 1.0232x over previous
//
#include <hip/hip_runtime.h>
#include <math.h>

#define BB 16
#define CIN 64
#define HH 64
#define WW 64
#define COUT 128
#define HW 4096          // HH*WW
#define CK 576           // CIN*9
#define VROW 612         // val row stride (shorts): 9 taps * 68 (64 + 4 pad)

typedef __attribute__((ext_vector_type(8))) short short8;
typedef __attribute__((ext_vector_type(4))) short short4v;
typedef __attribute__((ext_vector_type(4))) float f32x4;

// ---- workspace layout (float indices) ----
#define WT_OFF    0                         // wt2: 73728 shorts = 36864 floats
#define WPM_OFF   36864                     // wpm2: 18432 shorts = 9216 floats
#define XH_OFF    46080                     // xh: 4194304 shorts = 2097152 floats
#define YB_OFF    2143232                   // yb: 8388608 shorts = 4194304 floats
#define SAB_OFF   6337536                   // 256 floats
#define STAT_OFF  6337792                   // 64 slots * 256 floats

__device__ __forceinline__ short f2bf(float f) {
    union { float f; unsigned u; } cv; cv.f = f;
    unsigned u = cv.u;
    unsigned r = (u + 0x7fffu + ((u >> 16) & 1u)) >> 16;
    return (short)r;
}
__device__ __forceinline__ float bf2f(short s) {
    union { unsigned u; float f; } cv;
    cv.u = ((unsigned)(unsigned short)s) << 16;
    return cv.f;
}
__device__ __forceinline__ unsigned cvt_pk_bf16(float lo, float hi) {
    unsigned r;
    asm("v_cvt_pk_bf16_f32 %0, %1, %2" : "=v"(r) : "v"(lo), "v"(hi));
    return r;
}

// ---------------------------------------------------------------------------
// Kernel A: FUSED  (blocks <1024) x NCHW -> NHWC bf16  |  (blocks >=1024) weight pack
__global__ __launch_bounds__(256) void k_prep(const float* __restrict__ x,
                                              const float* __restrict__ wd,
                                              const float* __restrict__ wp,
                                              const float* __restrict__ wm,
                                              short* __restrict__ xh,
                                              short* __restrict__ wt2,
                                              short* __restrict__ wpm2) {
    const int blk = blockIdx.x;
    if (blk < 1024) {
        __shared__ float t[64][65];
        const int b    = blk >> 6;
        const int pos0 = (blk & 63) << 6;
        const int a    = threadIdx.x & 63;
        const int q    = threadIdx.x >> 6;
#pragma unroll
        for (int i = 0; i < 16; ++i) {
            int c = i * 4 + q;
            t[c][a] = x[((size_t)(b * CIN + c)) * HW + pos0 + a];
        }
        __syncthreads();
#pragma unroll
        for (int i = 0; i < 16; ++i) {
            int p = i * 4 + q;
            xh[((size_t)b * HW + pos0 + p) * CIN + a] = f2bf(t[a][p]);
        }
        return;
    }
    int i = (blk - 1024) * 256 + threadIdx.x;       // 360 blocks * 256 = 92160
    if (i < 18 * 128 * 32) {
        int kc  = i >> 12;
        int rem = i & 4095;
        int co  = rem >> 5;
        int kl  = rem & 31;
        int kk  = kc * 32 + kl;
        int k   = kk >> 6;
        int c   = kk & 63;
        wt2[i] = f2bf(wd[co * CK + c * 9 + k]);
        return;
    }
    i -= 18 * 128 * 32;
    if (i < 18 * 32 * 32) {
        int kc  = i >> 10;
        int rem = i & 1023;
        int t   = rem >> 5;
        int kl  = rem & 31;
        int kk  = kc * 32 + kl;
        int k   = kk >> 6;
        int c   = kk & 63;
        float v = 0.f;
        if (t < 18)      v = wp[t * CK + c * 9 + k];
        else if (t < 27) v = wm[(t - 18) * CK + c * 9 + k];
        wpm2[i] = f2bf(v);
    }
}

// ---------------------------------------------------------------------------
// Kernel 2: FUSED conv + deform + BN partials. MPB=32, 512 threads (8 waves).
// Hand-rolled counted-vmcnt prefetch rings (inline asm) in phases 0/2/3.
#define MPB 32
__global__ __launch_bounds__(512) void k_deform(const short* __restrict__ xh,
                                                const short* __restrict__ wt2,
                                                const short* __restrict__ wpm2,
                                                const float* __restrict__ bp,
                                                const float* __restrict__ bm,
                                                const float* __restrict__ bd,
                                                short* __restrict__ yb,
                                                float* __restrict__ gstat) {
    __shared__ short     val[MPB * VROW];    // 39168 B  [p][k*68 + c]
    __shared__ float     s_pm2[2][32][33];   // 8448 B   conv partials [kh][t][p]
    __shared__ unsigned  s_yx[MPB * 9];      // 1152 B
    __shared__ _Float16  s_wh[MPB * 9 * 4];  // 2304 B   -> 51072 B total

    const int bid  = blockIdx.x;                       // 2048
    const int swz  = (bid & 7) * 256 + (bid >> 3);     // XCD-chunked
    const int pos0 = swz * MPB;
    const int b   = pos0 >> 12;
    const int ho  = (pos0 >> 6) & 63;
    const int wo0 = pos0 & 63;                         // 0 or 32
    const int tid = threadIdx.x;
    const int wv   = tid >> 6;
    const int lane = tid & 63;
    const int l15  = lane & 15;
    const int lk   = lane >> 4;

    const short* xb = xh + (size_t)b * HW * CIN;

    // ---- phase 0: offset/mask conv, 8 waves K-split; asm prefetch ring ----
    {
        const int mw  = wv & 1;
        const int nw  = (wv >> 1) & 1;
        const int kh  = wv >> 2;
        const int kc0 = kh * 9;
        const int t   = nw * 16 + l15;
        const short* wr = wpm2 + t * 32 + lk * 8;
        const int wo = wo0 + mw * 16 + l15;

        short8 ab[3], bb[3];
        int    va[3];

#define P0_ISSUE(slot, kcl)                                                  \
        {   int kc = kc0 + (kcl);                                            \
            int k = kc >> 1; int c0 = (kc & 1) * 32 + lk * 8;                \
            int yy = ho - 1 + k / 3;                                         \
            int xx = wo - 1 + k % 3;                                         \
            va[slot] = (((unsigned)yy < 64u) & ((unsigned)xx < 64u)) ? -1 : 0; \
            int yyc = min(max(yy, 0), 63), xxc = min(max(xx, 0), 63);        \
            const short* ap_ = xb + (((yyc << 6) + xxc) << 6) + c0;          \
            const short* bp_ = wr + kc * 1024;                               \
            asm volatile("global_load_dwordx4 %0, %1, off"                   \
                         : "=&v"(ab[slot]) : "v"(ap_));                      \
            asm volatile("global_load_dwordx4 %0, %1, off"                   \
                         : "=&v"(bb[slot]) : "v"(bp_));                      \
        }

#define P0_STEP(i, VM)                                                      \
        {   asm volatile("s_waitcnt vmcnt(" #VM ")"                          \
                         : "+v"(ab[(i) % 3]), "+v"(bb[(i) % 3]));            \
            short8 a = ab[(i) % 3];                                          \
            if (!va[(i) % 3]) a = (short8)0;                                 \
            acc = __builtin_amdgcn_mfma_f32_16x16x32_bf16(a, bb[(i) % 3], acc, 0, 0, 0); \
            if ((i) + 3 < 9) P0_ISSUE((i) % 3, (i) + 3);                     \
        }

        f32x4 acc = (f32x4)(0.f);
        P0_ISSUE(0, 0) P0_ISSUE(1, 1) P0_ISSUE(2, 2)
        P0_STEP(0, 4) P0_STEP(1, 4) P0_STEP(2, 4)
        P0_STEP(3, 4) P0_STEP(4, 4) P0_STEP(5, 4)
        P0_STEP(6, 4) P0_STEP(7, 2) P0_STEP(8, 0)
#undef P0_ISSUE
#undef P0_STEP

#pragma unroll
        for (int j = 0; j < 4; ++j)
            s_pm2[kh][t][mw * 16 + lk * 4 + j] = acc[j];
    }
    __syncthreads();

    // ---- phase 1: sampling params (32 pos x 9 taps = 288) ----
    if (tid < MPB * 9) {
        int k = tid >> 5;               // 0..8
        int p = tid & 31;
        int wo = wo0 + p;
        float dy = s_pm2[0][2 * k    ][p] + s_pm2[1][2 * k    ][p] + bp[2 * k];
        float dx = s_pm2[0][2 * k + 1][p] + s_pm2[1][2 * k + 1][p] + bp[2 * k + 1];
        float mm = s_pm2[0][18 + k   ][p] + s_pm2[1][18 + k   ][p] + bm[k];
        float m  = 1.f / (1.f + expf(-mm));
        float py = (float)(ho - 1 + k / 3) + dy;
        float px = (float)(wo - 1 + k % 3) + dx;
        float fy = floorf(py), fx = floorf(px);
        float ly = py - fy, lx = px - fx;
        int y0 = (int)fy, x0 = (int)fx;
        int y1 = y0 + 1, x1 = x0 + 1;
        float vy0 = ((unsigned)y0 < 64u) ? 1.f : 0.f;
        float vy1 = ((unsigned)y1 < 64u) ? 1.f : 0.f;
        float vx0 = ((unsigned)x0 < 64u) ? 1.f : 0.f;
        float vx1 = ((unsigned)x1 < 64u) ? 1.f : 0.f;
        int y0c = min(max(y0, 0), 63), y1c = min(max(y1, 0), 63);
        int x0c = min(max(x0, 0), 63), x1c = min(max(x1, 0), 63);
        int tt = p * 9 + k;
        s_yx[tt] = (unsigned)y0c | ((unsigned)y1c << 8) | ((unsigned)x0c << 16) | ((unsigned)x1c << 24);
        s_wh[tt * 4 + 0] = (_Float16)((1.f - ly) * (1.f - lx) * m * vy0 * vx0);
        s_wh[tt * 4 + 1] = (_Float16)((1.f - ly) * lx * m * vy0 * vx1);
        s_wh[tt * 4 + 2] = (_Float16)(ly * (1.f - lx) * m * vy1 * vx0);
        s_wh[tt * 4 + 3] = (_Float16)(ly * lx * m * vy1 * vx1);
    }
    __syncthreads();

    // ---- phase 2: gather; asm prefetch ring depth-2 (iters 0..3) + tail ----
    {
        const int g  = tid >> 3;        // 0..63 groups
        const int li = tid & 7;
        const int c0 = li * 8;
        short8 cb[2][4];

#define P2_ISSUE(slot, IT)                                                   \
        {   int pr = (IT) * 64 + g;                                          \
            unsigned yx = s_yx[pr];                                          \
            int y0 = yx & 255, y1 = (yx >> 8) & 255;                         \
            int x0 = (yx >> 16) & 255, x1 = yx >> 24;                        \
            asm volatile("global_load_dwordx4 %0, %1, off"                   \
                : "=&v"(cb[slot][0]) : "v"(xb + (((y0 << 6) + x0) << 6) + c0)); \
            asm volatile("global_load_dwordx4 %0, %1, off"                   \
                : "=&v"(cb[slot][1]) : "v"(xb + (((y0 << 6) + x1) << 6) + c0)); \
            asm volatile("global_load_dwordx4 %0, %1, off"                   \
                : "=&v"(cb[slot][2]) : "v"(xb + (((y1 << 6) + x0) << 6) + c0)); \
            asm volatile("global_load_dwordx4 %0, %1, off"                   \
                : "=&v"(cb[slot][3]) : "v"(xb + (((y1 << 6) + x1) << 6) + c0)); \
        }

#define P2_BLEND(slot, IT, VM)                                               \
        {   asm volatile("s_waitcnt vmcnt(" #VM ")"                          \
                : "+v"(cb[slot][0]), "+v"(cb[slot][1]),                      \
                  "+v"(cb[slot][2]), "+v"(cb[slot][3]));                     \
            int pr = (IT) * 64 + g;                                          \
            int p = pr / 9, k = pr - p * 9;                                  \
            float w0 = (float)s_wh[pr * 4 + 0], w1 = (float)s_wh[pr * 4 + 1];\
            float w2 = (float)s_wh[pr * 4 + 2], w3 = (float)s_wh[pr * 4 + 3];\
            union { unsigned u[4]; short8 s; } pk;                           \
            _Pragma("unroll")                                                \
            for (int h = 0; h < 4; ++h) {                                    \
                float fa = w0*bf2f(cb[slot][0][2*h])   + w1*bf2f(cb[slot][1][2*h])   \
                         + w2*bf2f(cb[slot][2][2*h])   + w3*bf2f(cb[slot][3][2*h]);  \
                float fb = w0*bf2f(cb[slot][0][2*h+1]) + w1*bf2f(cb[slot][1][2*h+1]) \
                         + w2*bf2f(cb[slot][2][2*h+1]) + w3*bf2f(cb[slot][3][2*h+1]);\
                pk.u[h] = cvt_pk_bf16(fa, fb);                               \
            }                                                                \
            *(short8*)&val[p * VROW + k * 68 + c0] = pk.s;                   \
        }

        P2_ISSUE(0, 0)
        P2_ISSUE(1, 1) P2_BLEND(0, 0, 4)
        P2_ISSUE(0, 2) P2_BLEND(1, 1, 4)
        P2_ISSUE(1, 3) P2_BLEND(0, 2, 4)
        P2_BLEND(1, 3, 0)
#undef P2_ISSUE
#undef P2_BLEND

        if (g < 32) {                   // tail: pr = 256..287, plain code
            int pr = 256 + g;
            unsigned yx = s_yx[pr];
            int y0 = yx & 255, y1 = (yx >> 8) & 255;
            int x0 = (yx >> 16) & 255, x1 = yx >> 24;
            float w0 = (float)s_wh[pr * 4 + 0], w1 = (float)s_wh[pr * 4 + 1];
            float w2 = (float)s_wh[pr * 4 + 2], w3 = (float)s_wh[pr * 4 + 3];
            short8 v00 = *(const short8*)&xb[(((y0 << 6) + x0) << 6) + c0];
            short8 v01 = *(const short8*)&xb[(((y0 << 6) + x1) << 6) + c0];
            short8 v10 = *(const short8*)&xb[(((y1 << 6) + x0) << 6) + c0];
            short8 v11 = *(const short8*)&xb[(((y1 << 6) + x1) << 6) + c0];
            int p = pr / 9, k = pr - p * 9;
            union { unsigned u[4]; short8 s; } pk;
#pragma unroll
            for (int h = 0; h < 4; ++h) {
                float fa = w0 * bf2f(v00[2*h])   + w1 * bf2f(v01[2*h])
                         + w2 * bf2f(v10[2*h])   + w3 * bf2f(v11[2*h]);
                float fb = w0 * bf2f(v00[2*h+1]) + w1 * bf2f(v01[2*h+1])
                         + w2 * bf2f(v10[2*h+1]) + w3 * bf2f(v11[2*h+1]);
                pk.u[h] = cvt_pk_bf16(fa, fb);
            }
            *(short8*)&val[p * VROW + k * 68 + c0] = pk.s;
        }
    }
    __syncthreads();

    // ---- phase 3: wave owns co = wv*16..+15; asm B-ring depth-4 ----
    f32x4 acc0 = (f32x4)(0.f);      // positions 0..15
    f32x4 acc1 = (f32x4)(0.f);      // positions 16..31
    const short* wq = wt2 + (size_t)(wv * 16 + l15) * 32 + lk * 8;
    const int arow0 = l15 * VROW + lk * 8;
    const int arow1 = (l15 + 16) * VROW + lk * 8;
    {
        short8 bbf[4];

#define P3_ISSUE(slot, kc)                                                   \
        asm volatile("global_load_dwordx4 %0, %1, off"                       \
                     : "=&v"(bbf[slot]) : "v"(wq + (kc) * 4096));

#define P3_STEP(i, VM)                                                       \
        {   const int koff = ((i) >> 1) * 68 + ((i) & 1) * 32;               \
            short8 a0 = *(const short8*)&val[arow0 + koff];                  \
            short8 a1 = *(const short8*)&val[arow1 + koff];                  \
            asm volatile("s_waitcnt vmcnt(" #VM ")" : "+v"(bbf[(i) & 3]));   \
            acc0 = __builtin_amdgcn_mfma_f32_16x16x32_bf16(a0, bbf[(i) & 3], acc0, 0, 0, 0); \
            acc1 = __builtin_amdgcn_mfma_f32_16x16x32_bf16(a1, bbf[(i) & 3], acc1, 0, 0, 0); \
            if ((i) + 4 < 18) P3_ISSUE((i) & 3, (i) + 4);                    \
        }

        P3_ISSUE(0, 0) P3_ISSUE(1, 1) P3_ISSUE(2, 2) P3_ISSUE(3, 3)
        P3_STEP(0, 3)  P3_STEP(1, 3)  P3_STEP(2, 3)  P3_STEP(3, 3)
        P3_STEP(4, 3)  P3_STEP(5, 3)  P3_STEP(6, 3)  P3_STEP(7, 3)
        P3_STEP(8, 3)  P3_STEP(9, 3)  P3_STEP(10, 3) P3_STEP(11, 3)
        P3_STEP(12, 3) P3_STEP(13, 3) P3_STEP(14, 3) P3_STEP(15, 2)
        P3_STEP(16, 1) P3_STEP(17, 0)
#undef P3_ISSUE
#undef P3_STEP
    }

    // ---- epilogue: bf16 y writes (+bias) and BN partials (64-slot spread) ----
    const int co = wv * 16 + l15;
    {
        float bias = bd[co];
        short* ybp = yb + ((size_t)(b * COUT + co)) * HW + ho * WW + wo0;
        union { unsigned u[2]; short4v s; } o0, o1;
        o0.u[0] = cvt_pk_bf16(acc0[0] + bias, acc0[1] + bias);
        o0.u[1] = cvt_pk_bf16(acc0[2] + bias, acc0[3] + bias);
        *(short4v*)&ybp[lk * 4] = o0.s;
        o1.u[0] = cvt_pk_bf16(acc1[0] + bias, acc1[1] + bias);
        o1.u[1] = cvt_pk_bf16(acc1[2] + bias, acc1[3] + bias);
        *(short4v*)&ybp[16 + lk * 4] = o1.s;
    }
    float s0 = acc0[0] + acc0[1] + acc0[2] + acc0[3]
             + acc1[0] + acc1[1] + acc1[2] + acc1[3];
    float q0 = acc0[0]*acc0[0] + acc0[1]*acc0[1] + acc0[2]*acc0[2] + acc0[3]*acc0[3]
             + acc1[0]*acc1[0] + acc1[1]*acc1[1] + acc1[2]*acc1[2] + acc1[3]*acc1[3];
    s0 += __shfl_xor(s0, 16); s0 += __shfl_xor(s0, 32);
    q0 += __shfl_xor(q0, 16); q0 += __shfl_xor(q0, 32);
    if (lane < 16) {
        float* slot = gstat + (bid & 63) * 256;
        atomicAdd(&slot[wv * 16 + lane],       s0);
        atomicAdd(&slot[128 + wv * 16 + lane], q0);
    }
}

// ---------------------------------------------------------------------------
// Kernel 3: finalize BN scale/shift (reduce 64 slots, ILP-8)
__global__ __launch_bounds__(128) void k_finalize(const float* __restrict__ gstat,
                                                  const float* __restrict__ bd,
                                                  const float* __restrict__ gamma,
                                                  const float* __restrict__ beta,
                                                  float* __restrict__ sAB) {
    int c = threadIdx.x;
    float sa[4] = {0.f, 0.f, 0.f, 0.f};
    float qa[4] = {0.f, 0.f, 0.f, 0.f};
#pragma unroll
    for (int sl = 0; sl < 64; sl += 4) {
#pragma unroll
        for (int j = 0; j < 4; ++j) {
            sa[j] += gstat[(sl + j) * 256 + c];
            qa[j] += gstat[(sl + j) * 256 + 128 + c];
        }
    }
    float s = (sa[0] + sa[1]) + (sa[2] + sa[3]);
    float q = (qa[0] + qa[1]) + (qa[2] + qa[3]);
    const float invN = 1.f / (float)(BB * HW);
    float mean_acc = s * invN;
    float var = q * invN - mean_acc * mean_acc;
    float mean_y = mean_acc + bd[c];
    float A = gamma[c] * rsqrtf(var + 1e-5f);
    sAB[c]       = A;
    sAB[128 + c] = beta[c] - mean_y * A;
}

// ---------------------------------------------------------------------------
// Kernel 4: normalize + exact GELU. Reads bf16 y (16B/lane), writes f32 d_out.
__global__ __launch_bounds__(256) void k_norm_gelu(const short* __restrict__ yb,
                                                   const float* __restrict__ sAB,
                                                   float* __restrict__ out) {
    int i8 = blockIdx.x * 256 + threadIdx.x;        // 1048576 groups of 8
    if (i8 >= (BB * COUT * HW) / 8) return;
    int c = (i8 >> 9) & 127;
    float A  = sAB[c];
    float Bc = sAB[128 + c];
    short8 v = *(const short8*)&yb[(size_t)i8 * 8];
    float4 r0, r1;
    float t;
    t = bf2f(v[0]) * A + Bc; r0.x = 0.5f * t * (1.f + erff(t * 0.70710678118654752f));
    t = bf2f(v[1]) * A + Bc; r0.y = 0.5f * t * (1.f + erff(t * 0.70710678118654752f));
    t = bf2f(v[2]) * A + Bc; r0.z = 0.5f * t * (1.f + erff(t * 0.70710678118654752f));
    t = bf2f(v[3]) * A + Bc; r0.w = 0.5f * t * (1.f + erff(t * 0.70710678118654752f));
    t = bf2f(v[4]) * A + Bc; r1.x = 0.5f * t * (1.f + erff(t * 0.70710678118654752f));
    t = bf2f(v[5]) * A + Bc; r1.y = 0.5f * t * (1.f + erff(t * 0.70710678118654752f));
    t = bf2f(v[6]) * A + Bc; r1.z = 0.5f * t * (1.f + erff(t * 0.70710678118654752f));
    t = bf2f(v[7]) * A + Bc; r1.w = 0.5f * t * (1.f + erff(t * 0.70710678118654752f));
    *(float4*)&out[(size_t)i8 * 8]     = r0;
    *(float4*)&out[(size_t)i8 * 8 + 4] = r1;
}

// ---------------------------------------------------------------------------
extern "C" void kernel_launch(void* const* d_in, const int* in_sizes, int n_in,
                              void* d_out, int out_size, void* d_ws, size_t ws_size,
                              hipStream_t stream) {
    const float* x     = (const float*)d_in[0];
    const float* w_p   = (const float*)d_in[1];
    const float* b_p   = (const float*)d_in[2];
    const float* w_m   = (const float*)d_in[3];
    const float* b_m   = (const float*)d_in[4];
    const float* w_d   = (const float*)d_in[5];
    const float* b_d   = (const float*)d_in[6];
    const float* gamma = (const float*)d_in[7];
    const float* beta  = (const float*)d_in[8];
    float* ws  = (float*)d_ws;
    float* out = (float*)d_out;

    short* wt2  = (short*)(ws + WT_OFF);
    short* wpm2 = (short*)(ws + WPM_OFF);
    short* xh   = (short*)(ws + XH_OFF);
    short* yb   = (short*)(ws + YB_OFF);
    float* sAB  = ws + SAB_OFF;
    float* gstat= ws + STAT_OFF;

    hipMemsetAsync(gstat, 0, 64 * 256 * sizeof(float), stream);
    k_prep<<<dim3(1024 + 360), dim3(256), 0, stream>>>(x, w_d, w_p, w_m, xh, wt2, wpm2);
    k_deform<<<dim3(BB * HW / MPB), dim3(512), 0, stream>>>(xh, wt2, wpm2, b_p, b_m, b_d, yb, gstat);
    k_finalize<<<dim3(1), dim3(128), 0, stream>>>(gstat, b_d, gamma, beta, sAB);
    k_norm_gelu<<<dim3(BB * COUT * HW / 8 / 256), dim3(256), 0, stream>>>(yb, sAB, out);
}

// Round 16
// 84.149 us; speedup vs baseline: 1.3190x; 1.0041x over previous
//
#include <hip/hip_runtime.h>
#include <hip/hip_fp16.h>
#include <math.h>

#define BB 16
#define CIN 64
#define HH 64
#define WW 64
#define COUT 128
#define HW 4096          // HH*WW
#define CK 576           // CIN*9
#define VROW 612         // val row stride (f16): 9 taps * 68 (64 + 4 pad)

typedef _Float16 f16;
typedef __attribute__((ext_vector_type(8))) _Float16 f16x8;
typedef __attribute__((ext_vector_type(8))) short short8;
typedef __attribute__((ext_vector_type(4))) short short4v;
typedef __attribute__((ext_vector_type(4))) float f32x4;

// ---- workspace layout (float indices) ----
#define WT_OFF    0                         // wt2: 73728 f16 = 36864 floats
#define WPM_OFF   36864                     // wpm2: 18432 f16 = 9216 floats
#define XH_OFF    46080                     // xh: 4194304 f16 = 2097152 floats
#define YB_OFF    2143232                   // yb: 8388608 f16 = 4194304 floats
#define SAB_OFF   6337536                   // 256 floats
#define STAT_OFF  6337792                   // 64 slots * 256 floats

union U8h { short8 s; __half2 h[4]; f16x8 f; };
union U4h { short4v s; __half2 h[2]; };
union UWh { unsigned u; __half2 h; };

// ---------------------------------------------------------------------------
// Kernel A: FUSED  (blocks <1024) x NCHW -> NHWC f16  |  (blocks >=1024) weight pack
__global__ __launch_bounds__(256) void k_prep(const float* __restrict__ x,
                                              const float* __restrict__ wd,
                                              const float* __restrict__ wp,
                                              const float* __restrict__ wm,
                                              f16* __restrict__ xh,
                                              f16* __restrict__ wt2,
                                              f16* __restrict__ wpm2) {
    const int blk = blockIdx.x;
    if (blk < 1024) {
        __shared__ float t[64][65];
        const int b    = blk >> 6;
        const int pos0 = (blk & 63) << 6;
        // read: float4 along positions
        {
            const int c4 = threadIdx.x & 15;       // position quad
            const int cc = threadIdx.x >> 4;       // 16 channel groups
#pragma unroll
            for (int j = 0; j < 4; ++j) {
                int c = cc + j * 16;
                float4 v = *(const float4*)&x[((size_t)(b * CIN + c)) * HW + pos0 + c4 * 4];
                t[c][c4 * 4 + 0] = v.x;
                t[c][c4 * 4 + 1] = v.y;
                t[c][c4 * 4 + 2] = v.z;
                t[c][c4 * 4 + 3] = v.w;
            }
        }
        __syncthreads();
        // write: packed half2 (2 channels/lane)
        {
            const int a2 = (threadIdx.x & 31) * 2;
            const int q  = threadIdx.x >> 5;       // 0..7
#pragma unroll
            for (int i = 0; i < 8; ++i) {
                int p = i * 8 + q;
                __half2 hv = __halves2half2(__float2half(t[a2][p]),
                                            __float2half(t[a2 + 1][p]));
                UWh u; u.h = hv;
                *(unsigned*)&xh[((size_t)b * HW + pos0 + p) * CIN + a2] = u.u;
            }
        }
        return;
    }
    int i = (blk - 1024) * 256 + threadIdx.x;       // 360 blocks * 256 = 92160
    if (i < 18 * 128 * 32) {
        int kc  = i >> 12;
        int rem = i & 4095;
        int co  = rem >> 5;
        int kl  = rem & 31;
        int kk  = kc * 32 + kl;
        int k   = kk >> 6;
        int c   = kk & 63;
        wt2[i] = (f16)wd[co * CK + c * 9 + k];
        return;
    }
    i -= 18 * 128 * 32;
    if (i < 18 * 32 * 32) {
        int kc  = i >> 10;
        int rem = i & 1023;
        int t   = rem >> 5;
        int kl  = rem & 31;
        int kk  = kc * 32 + kl;
        int k   = kk >> 6;
        int c   = kk & 63;
        float v = 0.f;
        if (t < 18)      v = wp[t * CK + c * 9 + k];
        else if (t < 27) v = wm[(t - 18) * CK + c * 9 + k];
        wpm2[i] = (f16)v;
    }
}

// ---------------------------------------------------------------------------
// conv A-fragment loader (shifted-window NHWC patch, f16)
__device__ __forceinline__ f16x8 conv_a(const f16* __restrict__ xb,
                                        int ho, int wo, int lk, int kc) {
    const int k  = kc >> 1;
    const int c0 = (kc & 1) * 32 + lk * 8;
    const int yy = ho - 1 + k / 3;
    const int xx = wo - 1 + k % 3;
    const bool valid = ((unsigned)yy < 64u) & ((unsigned)xx < 64u);
    const int yyc = min(max(yy, 0), 63);
    const int xxc = min(max(xx, 0), 63);
    f16x8 a = *(const f16x8*)&xb[(((yyc << 6) + xxc) << 6) + c0];
    if (!valid) a = (f16x8)0;
    return a;
}

// ---------------------------------------------------------------------------
// Kernel 2: FUSED conv + deform + BN partials. MPB=32, 512 threads (8 waves).
// f16 pipeline: packed __hfma2 blend, mfma_f32_16x16x32_f16.
#define MPB 32
__global__ __launch_bounds__(512) void k_deform(const f16* __restrict__ xh,
                                                const f16* __restrict__ wt2,
                                                const f16* __restrict__ wpm2,
                                                const float* __restrict__ bp,
                                                const float* __restrict__ bm,
                                                const float* __restrict__ bd,
                                                f16* __restrict__ yb,
                                                float* __restrict__ gstat) {
    __shared__ f16       val[MPB * VROW];    // 39168 B  [p][k*68 + c]
    __shared__ float     s_pm2[2][28][33];   // 7392 B   conv partials [kh][t][p], t<28
    __shared__ unsigned  s_yx[MPB * 9];      // 1152 B
    __shared__ unsigned  s_w[MPB * 9 * 4];   // 4608 B   half2-broadcast weights
    // total 52320 B -> 3 blocks/CU

    const int bid  = blockIdx.x;                       // 2048
    const int swz  = (bid & 7) * 256 + (bid >> 3);     // XCD-chunked
    const int pos0 = swz * MPB;
    const int b   = pos0 >> 12;
    const int ho  = (pos0 >> 6) & 63;
    const int wo0 = pos0 & 63;                         // 0 or 32
    const int tid = threadIdx.x;
    const int wv   = tid >> 6;
    const int lane = tid & 63;
    const int l15  = lane & 15;
    const int lk   = lane >> 4;

    const f16* xb = xh + (size_t)b * HW * CIN;

    // ---- phase 0: offset/mask conv, all 8 waves, K-split ----
    {
        const int mw = wv & 1;          // position half
        const int nw = (wv >> 1) & 1;   // channel half
        const int kh = wv >> 2;         // K half
        const int t  = nw * 16 + l15;   // out channel 0..31 (>=27 uses zero rows)
        const f16* wr = wpm2 + t * 32 + lk * 8;
        const int wo = wo0 + mw * 16 + l15;
        f32x4 acc = (f32x4)(0.f);
#pragma unroll
        for (int kc = kh * 9; kc < kh * 9 + 9; ++kc) {
            f16x8 a  = conv_a(xb, ho, wo, lk, kc);
            f16x8 bf = *(const f16x8*)&wr[kc * 1024];
            acc = __builtin_amdgcn_mfma_f32_16x16x32_f16(a, bf, acc, 0, 0, 0);
        }
        if (t < 28) {
#pragma unroll
            for (int j = 0; j < 4; ++j)
                s_pm2[kh][t][mw * 16 + lk * 4 + j] = acc[j];
        }
    }
    __syncthreads();

    // ---- phase 1: sampling params (32 pos x 9 taps = 288) ----
    if (tid < MPB * 9) {
        int k = tid >> 5;               // 0..8
        int p = tid & 31;
        int wo = wo0 + p;
        float dy = s_pm2[0][2 * k    ][p] + s_pm2[1][2 * k    ][p] + bp[2 * k];
        float dx = s_pm2[0][2 * k + 1][p] + s_pm2[1][2 * k + 1][p] + bp[2 * k + 1];
        float mm = s_pm2[0][18 + k   ][p] + s_pm2[1][18 + k   ][p] + bm[k];
        float m  = 1.f / (1.f + expf(-mm));
        float py = (float)(ho - 1 + k / 3) + dy;
        float px = (float)(wo - 1 + k % 3) + dx;
        float fy = floorf(py), fx = floorf(px);
        float ly = py - fy, lx = px - fx;
        int y0 = (int)fy, x0 = (int)fx;
        int y1 = y0 + 1, x1 = x0 + 1;
        float vy0 = ((unsigned)y0 < 64u) ? 1.f : 0.f;
        float vy1 = ((unsigned)y1 < 64u) ? 1.f : 0.f;
        float vx0 = ((unsigned)x0 < 64u) ? 1.f : 0.f;
        float vx1 = ((unsigned)x1 < 64u) ? 1.f : 0.f;
        int y0c = min(max(y0, 0), 63), y1c = min(max(y1, 0), 63);
        int x0c = min(max(x0, 0), 63), x1c = min(max(x1, 0), 63);
        int tt = p * 9 + k;
        s_yx[tt] = (unsigned)y0c | ((unsigned)y1c << 8) | ((unsigned)x0c << 16) | ((unsigned)x1c << 24);
        float w0 = (1.f - ly) * (1.f - lx) * m * vy0 * vx0;
        float w1 = (1.f - ly) * lx * m * vy0 * vx1;
        float w2 = ly * (1.f - lx) * m * vy1 * vx0;
        float w3 = ly * lx * m * vy1 * vx1;
        s_w[tt * 4 + 0] = (unsigned)__half_as_ushort(__float2half(w0)) * 0x10001u;
        s_w[tt * 4 + 1] = (unsigned)__half_as_ushort(__float2half(w1)) * 0x10001u;
        s_w[tt * 4 + 2] = (unsigned)__half_as_ushort(__float2half(w2)) * 0x10001u;
        s_w[tt * 4 + 3] = (unsigned)__half_as_ushort(__float2half(w3)) * 0x10001u;
    }
    __syncthreads();

    // ---- phase 2: gather; 64 groups x 8 lanes; packed __hfma2 blend ----
    {
        const int g  = tid >> 3;        // 0..63 groups
        const int li = tid & 7;
        const int c0 = li * 8;
#pragma unroll
        for (int it = 0; it < 5; ++it) {
            int pr = it * 64 + g;       // 0..319, guard 288
            if (pr < MPB * 9) {
                unsigned yx = s_yx[pr];
                int y0 = yx & 255, y1 = (yx >> 8) & 255;
                int x0 = (yx >> 16) & 255, x1 = yx >> 24;
                UWh w0u, w1u, w2u, w3u;
                w0u.u = s_w[pr * 4 + 0];
                w1u.u = s_w[pr * 4 + 1];
                w2u.u = s_w[pr * 4 + 2];
                w3u.u = s_w[pr * 4 + 3];
                U8h v00, v01, v10, v11, o;
                v00.s = *(const short8*)&xb[(((y0 << 6) + x0) << 6) + c0];
                v01.s = *(const short8*)&xb[(((y0 << 6) + x1) << 6) + c0];
                v10.s = *(const short8*)&xb[(((y1 << 6) + x0) << 6) + c0];
                v11.s = *(const short8*)&xb[(((y1 << 6) + x1) << 6) + c0];
                int p = pr / 9, k = pr - p * 9;
#pragma unroll
                for (int h2 = 0; h2 < 4; ++h2) {
                    o.h[h2] = __hfma2(v00.h[h2], w0u.h,
                              __hfma2(v01.h[h2], w1u.h,
                              __hfma2(v10.h[h2], w2u.h,
                              __hmul2(v11.h[h2], w3u.h))));
                }
                *(short8*)&val[p * VROW + k * 68 + c0] = o.s;   // ds_write_b128
            }
        }
    }
    __syncthreads();

    // ---- phase 3: wave owns co = wv*16..+15; B read once per block ----
    f32x4 acc0 = (f32x4)(0.f);      // positions 0..15
    f32x4 acc1 = (f32x4)(0.f);      // positions 16..31
    const f16* wq = wt2 + (size_t)(wv * 16 + l15) * 32 + lk * 8;
    const int arow0 = l15 * VROW + lk * 8;
    const int arow1 = (l15 + 16) * VROW + lk * 8;
#pragma unroll
    for (int kc = 0; kc < 18; ++kc) {
        const int koff = (kc >> 1) * 68 + (kc & 1) * 32;
        f16x8 a0 = *(const f16x8*)&val[arow0 + koff];
        f16x8 a1 = *(const f16x8*)&val[arow1 + koff];
        f16x8 bf = *(const f16x8*)&wq[kc * 4096];
        acc0 = __builtin_amdgcn_mfma_f32_16x16x32_f16(a0, bf, acc0, 0, 0, 0);
        acc1 = __builtin_amdgcn_mfma_f32_16x16x32_f16(a1, bf, acc1, 0, 0, 0);
    }

    // ---- epilogue: f16 y writes (+bias) and BN partials (64-slot spread) ----
    const int co = wv * 16 + l15;
    {
        float bias = bd[co];
        f16* ybp = yb + ((size_t)(b * COUT + co)) * HW + ho * WW + wo0;
        U4h o0, o1;
        o0.h[0] = __halves2half2(__float2half(acc0[0] + bias), __float2half(acc0[1] + bias));
        o0.h[1] = __halves2half2(__float2half(acc0[2] + bias), __float2half(acc0[3] + bias));
        *(short4v*)&ybp[lk * 4] = o0.s;
        o1.h[0] = __halves2half2(__float2half(acc1[0] + bias), __float2half(acc1[1] + bias));
        o1.h[1] = __halves2half2(__float2half(acc1[2] + bias), __float2half(acc1[3] + bias));
        *(short4v*)&ybp[16 + lk * 4] = o1.s;
    }
    float s0 = acc0[0] + acc0[1] + acc0[2] + acc0[3]
             + acc1[0] + acc1[1] + acc1[2] + acc1[3];
    float q0 = acc0[0]*acc0[0] + acc0[1]*acc0[1] + acc0[2]*acc0[2] + acc0[3]*acc0[3]
             + acc1[0]*acc1[0] + acc1[1]*acc1[1] + acc1[2]*acc1[2] + acc1[3]*acc1[3];
    s0 += __shfl_xor(s0, 16); s0 += __shfl_xor(s0, 32);
    q0 += __shfl_xor(q0, 16); q0 += __shfl_xor(q0, 32);
    if (lane < 16) {
        float* slot = gstat + (bid & 63) * 256;
        atomicAdd(&slot[wv * 16 + lane],       s0);
        atomicAdd(&slot[128 + wv * 16 + lane], q0);
    }
}

// ---------------------------------------------------------------------------
// Kernel 3: finalize BN scale/shift (reduce 64 slots, ILP-4)
__global__ __launch_bounds__(128) void k_finalize(const float* __restrict__ gstat,
                                                  const float* __restrict__ bd,
                                                  const float* __restrict__ gamma,
                                                  const float* __restrict__ beta,
                                                  float* __restrict__ sAB) {
    int c = threadIdx.x;
    float sa[4] = {0.f, 0.f, 0.f, 0.f};
    float qa[4] = {0.f, 0.f, 0.f, 0.f};
#pragma unroll
    for (int sl = 0; sl < 64; sl += 4) {
#pragma unroll
        for (int j = 0; j < 4; ++j) {
            sa[j] += gstat[(sl + j) * 256 + c];
            qa[j] += gstat[(sl + j) * 256 + 128 + c];
        }
    }
    float s = (sa[0] + sa[1]) + (sa[2] + sa[3]);
    float q = (qa[0] + qa[1]) + (qa[2] + qa[3]);
    const float invN = 1.f / (float)(BB * HW);
    float mean_acc = s * invN;
    float var = q * invN - mean_acc * mean_acc;
    float mean_y = mean_acc + bd[c];
    float A = gamma[c] * rsqrtf(var + 1e-5f);
    sAB[c]       = A;
    sAB[128 + c] = beta[c] - mean_y * A;
}

// ---------------------------------------------------------------------------
// Kernel 4: normalize + exact GELU. Reads f16 y (16B/lane), writes f32 d_out.
__global__ __launch_bounds__(256) void k_norm_gelu(const f16* __restrict__ yb,
                                                   const float* __restrict__ sAB,
                                                   float* __restrict__ out) {
    int i8 = blockIdx.x * 256 + threadIdx.x;        // 1048576 groups of 8
    if (i8 >= (BB * COUT * HW) / 8) return;
    int c = (i8 >> 9) & 127;
    float A  = sAB[c];
    float Bc = sAB[128 + c];
    f16x8 v = *(const f16x8*)&yb[(size_t)i8 * 8];
    float4 r0, r1;
    float t;
    t = (float)v[0] * A + Bc; r0.x = 0.5f * t * (1.f + erff(t * 0.70710678118654752f));
    t = (float)v[1] * A + Bc; r0.y = 0.5f * t * (1.f + erff(t * 0.70710678118654752f));
    t = (float)v[2] * A + Bc; r0.z = 0.5f * t * (1.f + erff(t * 0.70710678118654752f));
    t = (float)v[3] * A + Bc; r0.w = 0.5f * t * (1.f + erff(t * 0.70710678118654752f));
    t = (float)v[4] * A + Bc; r1.x = 0.5f * t * (1.f + erff(t * 0.70710678118654752f));
    t = (float)v[5] * A + Bc; r1.y = 0.5f * t * (1.f + erff(t * 0.70710678118654752f));
    t = (float)v[6] * A + Bc; r1.z = 0.5f * t * (1.f + erff(t * 0.70710678118654752f));
    t = (float)v[7] * A + Bc; r1.w = 0.5f * t * (1.f + erff(t * 0.70710678118654752f));
    *(float4*)&out[(size_t)i8 * 8]     = r0;
    *(float4*)&out[(size_t)i8 * 8 + 4] = r1;
}

// ---------------------------------------------------------------------------
extern "C" void kernel_launch(void* const* d_in, const int* in_sizes, int n_in,
                              void* d_out, int out_size, void* d_ws, size_t ws_size,
                              hipStream_t stream) {
    const float* x     = (const float*)d_in[0];
    const float* w_p   = (const float*)d_in[1];
    const float* b_p   = (const float*)d_in[2];
    const float* w_m   = (const float*)d_in[3];
    const float* b_m   = (const float*)d_in[4];
    const float* w_d   = (const float*)d_in[5];
    const float* b_d   = (const float*)d_in[6];
    const float* gamma = (const float*)d_in[7];
    const float* beta  = (const float*)d_in[8];
    float* ws  = (float*)d_ws;
    float* out = (float*)d_out;

    f16*  wt2  = (f16*)(ws + WT_OFF);
    f16*  wpm2 = (f16*)(ws + WPM_OFF);
    f16*  xh   = (f16*)(ws + XH_OFF);
    f16*  yb   = (f16*)(ws + YB_OFF);
    float* sAB  = ws + SAB_OFF;
    float* gstat= ws + STAT_OFF;

    hipMemsetAsync(gstat, 0, 64 * 256 * sizeof(float), stream);
    k_prep<<<dim3(1024 + 360), dim3(256), 0, stream>>>(x, w_d, w_p, w_m, xh, wt2, wpm2);
    k_deform<<<dim3(BB * HW / MPB), dim3(512), 0, stream>>>(xh, wt2, wpm2, b_p, b_m, b_d, yb, gstat);
    k_finalize<<<dim3(1), dim3(128), 0, stream>>>(gstat, b_d, gamma, beta, sAB);
    k_norm_gelu<<<dim3(BB * COUT * HW / 8 / 256), dim3(256), 0, stream>>>(yb, sAB, out);
}